// Round 8
// baseline (553.594 us; speedup 1.0000x reference)
//
#include <hip/hip_runtime.h>
#include <hip/hip_bf16.h>

#define N_NODES 50000
#define N_EDGES 300000
#define HIDDEN 256
#define ZDIM 128
#define NLAYERS 3
#define NGRAPHS 16
#define EPS 1e-5f
#define NSCANBLK 196   // ceil(50000/256)

// ---- fp32 param region offsets (floats) ----
#define OFF_POS    0
#define OFF_WIN    150000
#define OFF_BIN    150768
#define OFF_GIN    151024
#define OFF_BEIN   151280
#define OFF_CONVB  348144
#define OFF_GNG    348912
#define OFF_GNB    349680
#define OFF_WO1    350448
#define OFF_BO1    415984
#define OFF_GO     416240
#define OFF_BEO    416496
#define OFF_WO2    416752
#define OFF_BO2    449520
#define PARAMS_TOTAL 449648

typedef __attribute__((ext_vector_type(8))) short short8;
typedef __attribute__((ext_vector_type(4))) float floatx4;

__device__ inline float wave_reduce_sum(float v){
#pragma unroll
  for (int off = 32; off; off >>= 1) v += __shfl_xor(v, off);
  return v;
}

__device__ inline ushort f2bf(float f){
  __hip_bfloat16 t = __float2bfloat16(f);
  return *(ushort*)&t;
}
__device__ inline float bflo(unsigned int u){ return __uint_as_float(u << 16); }
__device__ inline float bfhi(unsigned int u){ return __uint_as_float(u & 0xffff0000u); }

__device__ inline void gload_lds16(const void* g, void* l){
  __builtin_amdgcn_global_load_lds((const __attribute__((address_space(1))) void*)g,
                                   (__attribute__((address_space(3))) void*)l, 16, 0, 0);
}

struct PrepArgs { const void* src[14]; int n[14]; int off[14]; const void* win; const void* convw; };

// fused: per-block dtype detect + param convert (14 tensors) + Wt build (transposed bf16 conv_W)
__global__ __launch_bounds__(256) void k_prep(PrepArgs a, float* __restrict__ params,
                                              ushort* __restrict__ Wt, int* __restrict__ flag){
  __shared__ int sf;
  int tid = threadIdx.x;
  if (tid == 0) sf = 0;
  __syncthreads();
  const unsigned short* w = (const unsigned short*)a.win;
  for (int i = tid; i < 768; i += 256){
    int e = (w[i] >> 7) & 0xff;            // bf16 exponent field
    if (e >= 148) atomicOr(&sf, 1);        // |v|>=2^20: impossible for real bf16 weights
  }
  __syncthreads();
  const bool isf32 = (sf != 0);
  if (blockIdx.x == 0 && tid == 0) *flag = sf;

  int stride = gridDim.x * blockDim.x;
  int t0 = blockIdx.x * blockDim.x + tid;
  for (int s = 0; s < 14; ++s){
    const void* src = a.src[s];
    int n = a.n[s];
    float* dst = params + a.off[s];
    if (isf32){
      const float* f = (const float*)src;
      for (int i = t0; i < n; i += stride) dst[i] = f[i];
    } else {
      const unsigned short* u = (const unsigned short*)src;
      for (int i = t0; i < n; i += stride) dst[i] = bflo(u[i]);
    }
  }
  // Wt[l][n][k] = conv_W[l][k][n] as bf16, read directly from source
  for (int idx = t0; idx < NLAYERS * 65536; idx += stride){
    int l = idx >> 16, rem = idx & 65535, n = rem >> 8, k = rem & 255;
    int si = l * 65536 + k * 256 + n;
    float v = isf32 ? ((const float*)a.convw)[si] : bflo(((const unsigned short*)a.convw)[si]);
    Wt[idx] = f2bf(v);
  }
}

__global__ void k_init(int* __restrict__ deg, int* __restrict__ fill,
                       float* __restrict__ pooled, float* __restrict__ counts){
  int i = blockIdx.x * blockDim.x + threadIdx.x;
  if (i < N_NODES){ deg[i] = 1; fill[i] = 0; }       // self-loop contributes 1
  if (i < NGRAPHS * 256) pooled[i] = 0.f;
  if (i < NGRAPHS) counts[i] = 0.f;
}

__global__ void k_deg(const int* __restrict__ dst, int* __restrict__ deg){
  int e = blockIdx.x * blockDim.x + threadIdx.x;
  if (e < N_EDGES) atomicAdd(&deg[dst[e]], 1);
}

// ---- hierarchical exclusive scan of deg -> row_start (+ fused dinv) ----
__global__ __launch_bounds__(256) void k_scan1(const int* __restrict__ deg, int* __restrict__ row_start,
                                               int* __restrict__ bsum, float* __restrict__ dinv){
  __shared__ int sd[256];
  int tid = threadIdx.x;
  int i = blockIdx.x * 256 + tid;
  int v = (i < N_NODES) ? deg[i] : 0;
  if (i < N_NODES) dinv[i] = rsqrtf((float)v);
  sd[tid] = v;
  __syncthreads();
#pragma unroll
  for (int off = 1; off < 256; off <<= 1){
    int t = (tid >= off) ? sd[tid - off] : 0;
    __syncthreads();
    sd[tid] += t;
    __syncthreads();
  }
  if (i < N_NODES) row_start[i] = sd[tid];
  if (tid == 255) bsum[blockIdx.x] = sd[255];
}

__global__ __launch_bounds__(256) void k_scan2(const int* __restrict__ bsum, int* __restrict__ boff,
                                               int* __restrict__ row_start){
  __shared__ int sd[256];
  int tid = threadIdx.x;
  int v = (tid < NSCANBLK) ? bsum[tid] : 0;
  sd[tid] = v;
  __syncthreads();
#pragma unroll
  for (int off = 1; off < 256; off <<= 1){
    int t = (tid >= off) ? sd[tid - off] : 0;
    __syncthreads();
    sd[tid] += t;
    __syncthreads();
  }
  if (tid < NSCANBLK) boff[tid] = sd[tid] - v;   // exclusive
  if (tid == NSCANBLK - 1) row_start[N_NODES] = sd[tid];
}

__global__ __launch_bounds__(256) void k_scan3(const int* __restrict__ deg, const int* __restrict__ boff,
                                               int* __restrict__ row_start){
  int i = blockIdx.x * 256 + threadIdx.x;
  if (i < N_NODES) row_start[i] = row_start[i] + boff[blockIdx.x] - deg[i];
}

__global__ void k_fill(const int* __restrict__ src, const int* __restrict__ dst,
                       const int* __restrict__ row_start, int* __restrict__ fill,
                       const float* __restrict__ dinv,
                       int* __restrict__ csr_src, float* __restrict__ csr_w){
  int t = blockIdx.x * blockDim.x + threadIdx.x;
  if (t >= N_EDGES + N_NODES) return;
  int s, d;
  if (t < N_EDGES){ s = src[t]; d = dst[t]; }
  else            { s = t - N_EDGES; d = s; }      // self loops
  int pos = row_start[d] + atomicAdd(&fill[d], 1);
  csr_src[pos] = s;
  csr_w[pos] = dinv[s] * dinv[d];
}

// input projection: Linear(3,256) -> ReLU -> GroupNorm(1,256). one wave per node. bf16 out.
__global__ __launch_bounds__(256) void k_input_proj(const float* __restrict__ params,
                                                    ushort* __restrict__ x_bf){
  int lane = threadIdx.x & 63;
  int node = (blockIdx.x << 2) + (threadIdx.x >> 6);
  if (node >= N_NODES) return;
  const float* pos = params + OFF_POS + node * 3;
  float px = pos[0], py = pos[1], pz = pos[2];
  int c = lane * 4;
  const float* w0 = params + OFF_WIN;
  float v[4];
#pragma unroll
  for (int j = 0; j < 4; ++j){
    float t = params[OFF_BIN + c + j];
    t = fmaf(px, w0[c + j], t);
    t = fmaf(py, w0[256 + c + j], t);
    t = fmaf(pz, w0[512 + c + j], t);
    v[j] = fmaxf(t, 0.f);
  }
  float s  = v[0] + v[1] + v[2] + v[3];
  float ss = v[0]*v[0] + v[1]*v[1] + v[2]*v[2] + v[3]*v[3];
  s = wave_reduce_sum(s); ss = wave_reduce_sum(ss);
  float mean = s * (1.f/256.f);
  float var  = ss * (1.f/256.f) - mean * mean;
  float inv  = rsqrtf(var + EPS);
  float4 o;
  o.x = (v[0]-mean)*inv*params[OFF_GIN+c+0] + params[OFF_BEIN+c+0];
  o.y = (v[1]-mean)*inv*params[OFF_GIN+c+1] + params[OFF_BEIN+c+1];
  o.z = (v[2]-mean)*inv*params[OFF_GIN+c+2] + params[OFF_BEIN+c+2];
  o.w = (v[3]-mean)*inv*params[OFF_GIN+c+3] + params[OFF_BEIN+c+3];
  ushort4 ob = { f2bf(o.x), f2bf(o.y), f2bf(o.z), f2bf(o.w) };
  *(ushort4*)(x_bf + node * 256 + c) = ob;
}

// ===== fused GCN layer: xout = relu(groupnorm(Agg(xin) @ W + b)) + xin =====
// Uses Agg(x·W) == Agg(x)·W. One block = 64 nodes. Phase 1: each wave gathers 16
// nodes' weighted neighbor sums into a swizzled LDS A-tile (bf16). Phase 2: MFMA
// 64x256 GEMM vs Wt (B staged per-64K-chunk via global_load_lds, round-7 layout).
// Phase 3: bias + cross-wave GroupNorm + ReLU + residual, store to xout (ping-pong).
#define LBM 64
__global__ __launch_bounds__(256) void k_layer(const ushort* __restrict__ xin, ushort* __restrict__ xout,
    const int* __restrict__ row_start, const int* __restrict__ csr_src, const float* __restrict__ csr_w,
    const ushort* __restrict__ Bt, const float* __restrict__ params, int layer){
  __shared__ __align__(16) ushort As[LBM * 256];   // 32 KB, XOR-swizzled granules
  __shared__ __align__(16) ushort Bs[256 * 64];    // 32 KB, round-7 layout
  __shared__ float rsum[4][LBM], rsq[4][LBM];
  __shared__ float mmean[LBM], minv[LBM];
  int tid = threadIdx.x;
  int wave = tid >> 6, lane = tid & 63;
  int q = lane >> 4, l15 = lane & 15;
  int srow = lane >> 3, sg = lane & 7;
  int row0 = blockIdx.x * LBM;

  // issue async B stage for k0=0 up front (overlaps the gather phase)
#pragma unroll
  for (int t = 0; t < 8; ++t){
    int rg = wave * 8 + t;               // 32 rowgroups x 8 rows = 256 W-rows
    int r = rg * 8 + srow;
    int gs = sg ^ (r & 7);
    gload_lds16(Bt + (size_t)r * 256 + 0 + gs * 8, Bs + rg * 512);
  }

  // phase 1: gather. wave aggregates nodes row0+wave*16 .. +15; lane holds 4 channels.
  int c = lane * 4;
  for (int t = 0; t < 16; ++t){
    int nloc = wave * 16 + t;
    int node = row0 + nloc;
    float a0 = 0.f, a1 = 0.f, a2 = 0.f, a3 = 0.f;
    if (node < N_NODES){
      int p0 = row_start[node], p1 = row_start[node + 1];
      int p = p0;
      for (; p + 8 <= p1; p += 8){
        int s[8]; float w[8]; uint2 v[8];
#pragma unroll
        for (int j = 0; j < 8; ++j){ s[j] = csr_src[p + j]; w[j] = csr_w[p + j]; }
#pragma unroll
        for (int j = 0; j < 8; ++j) v[j] = *(const uint2*)(xin + (size_t)s[j] * 256 + c);
#pragma unroll
        for (int j = 0; j < 8; ++j){
          a0 = fmaf(w[j], bflo(v[j].x), a0); a1 = fmaf(w[j], bfhi(v[j].x), a1);
          a2 = fmaf(w[j], bflo(v[j].y), a2); a3 = fmaf(w[j], bfhi(v[j].y), a3);
        }
      }
      for (; p < p1; ++p){
        int s0 = csr_src[p]; float w0 = csr_w[p];
        uint2 v0 = *(const uint2*)(xin + (size_t)s0 * 256 + c);
        a0 = fmaf(w0, bflo(v0.x), a0); a1 = fmaf(w0, bfhi(v0.x), a1);
        a2 = fmaf(w0, bflo(v0.y), a2); a3 = fmaf(w0, bfhi(v0.y), a3);
      }
    }
    // write m row to LDS: logical granule g=lane>>1 -> swizzled g^(nloc&7), half lane&1
    int gp = (lane >> 1) ^ (nloc & 7);
    ushort4 mv = { f2bf(a0), f2bf(a1), f2bf(a2), f2bf(a3) };
    *(ushort4*)(As + nloc * 256 + gp * 8 + (lane & 1) * 4) = mv;
  }
  __syncthreads();   // As complete; Bs k0=0 landed (barrier drains vmcnt)

  // phase 2: MFMA. wave owns all 64 rows x cols [wave*64, wave*64+64).
  floatx4 acc[4][4] = {};
  for (int k0 = 0; k0 < 256; k0 += 64){
    if (k0 > 0){
      __syncthreads();                   // prior chunk's MFMA reads done
#pragma unroll
      for (int t = 0; t < 8; ++t){
        int rg = wave * 8 + t;
        int r = rg * 8 + srow;
        int gs = sg ^ (r & 7);
        gload_lds16(Bt + (size_t)r * 256 + k0 + gs * 8, Bs + rg * 512);
      }
      __syncthreads();
    }
#pragma unroll
    for (int kk = 0; kk < 64; kk += 32){
      short8 af[4], bfr[4];
#pragma unroll
      for (int i = 0; i < 4; ++i){
        int R = i * 16 + l15;
        int lg = ((k0 + kk) >> 3) + q;
        af[i] = *(const short8*)(As + R * 256 + ((lg ^ (R & 7)) << 3));
      }
#pragma unroll
      for (int j = 0; j < 4; ++j){
        int C = wave * 64 + j * 16 + l15;
        int bg = (kk >> 3) + q;
        bfr[j] = *(const short8*)(Bs + C * 64 + ((bg ^ (C & 7)) << 3));
      }
#pragma unroll
      for (int i = 0; i < 4; ++i)
#pragma unroll
        for (int j = 0; j < 4; ++j)
          acc[i][j] = __builtin_amdgcn_mfma_f32_16x16x32_bf16(af[i], bfr[j], acc[i][j], 0, 0, 0);
    }
  }

  // phase 3: bias + GroupNorm(256) + ReLU + residual
  const float* cb = params + OFF_CONVB + layer * 256;
  const float* gw = params + OFF_GNG  + layer * 256;
  const float* bw = params + OFF_GNB  + layer * 256;
  float cbv[4], gv[4], bv[4];
#pragma unroll
  for (int j = 0; j < 4; ++j){
    int C = wave * 64 + j * 16 + l15;
    cbv[j] = cb[C]; gv[j] = gw[C]; bv[j] = bw[C];
  }
  float psum[4][4], psq[4][4];
#pragma unroll
  for (int i = 0; i < 4; ++i)
#pragma unroll
    for (int r = 0; r < 4; ++r){
      float s = 0.f, s2 = 0.f;
#pragma unroll
      for (int j = 0; j < 4; ++j){
        float v = acc[i][j][r] + cbv[j];
        acc[i][j][r] = v;
        s += v; s2 += v * v;
      }
      psum[i][r] = s; psq[i][r] = s2;
    }
#pragma unroll
  for (int off = 1; off < 16; off <<= 1){
#pragma unroll
    for (int i = 0; i < 4; ++i)
#pragma unroll
      for (int r = 0; r < 4; ++r){
        psum[i][r] += __shfl_xor(psum[i][r], off);
        psq[i][r]  += __shfl_xor(psq[i][r], off);
      }
  }
  if (l15 == 0){
#pragma unroll
    for (int i = 0; i < 4; ++i)
#pragma unroll
      for (int r = 0; r < 4; ++r){
        int row = i * 16 + q * 4 + r;
        rsum[wave][row] = psum[i][r];
        rsq[wave][row]  = psq[i][r];
      }
  }
  __syncthreads();
  if (tid < LBM){
    float t0 = rsum[0][tid] + rsum[1][tid] + rsum[2][tid] + rsum[3][tid];
    float t1 = rsq[0][tid]  + rsq[1][tid]  + rsq[2][tid]  + rsq[3][tid];
    float mean = t0 * (1.f/256.f);
    float var  = t1 * (1.f/256.f) - mean * mean;
    mmean[tid] = mean;
    minv[tid]  = rsqrtf(var + EPS);
  }
  __syncthreads();
#pragma unroll
  for (int i = 0; i < 4; ++i){
#pragma unroll
    for (int r = 0; r < 4; ++r){
      int row = i * 16 + q * 4 + r;
      int grow = row0 + row;
      if (grow < N_NODES){
        float mean = mmean[row], inv = minv[row];
#pragma unroll
        for (int j = 0; j < 4; ++j){
          int col = wave * 64 + j * 16 + l15;
          float vn = (acc[i][j][r] - mean) * inv * gv[j] + bv[j];
          float o = fmaxf(vn, 0.f) + bflo((unsigned int)xin[(size_t)grow * 256 + col]);
          xout[(size_t)grow * 256 + col] = f2bf(o);
        }
      }
    }
  }
}

// global mean pool: 196 blocks x 256 nodes; wave owns 64 nodes, 8-deep load unroll;
// LDS [16][256] block accumulator; one global-atomic row flush per graph present in block.
#define PBLK 256
__global__ __launch_bounds__(256) void k_pool(const ushort* __restrict__ x_bf, const int* __restrict__ batch,
                                              float* __restrict__ pooled, float* __restrict__ counts){
  __shared__ float lacc[NGRAPHS][256];
  __shared__ float lcnt[NGRAPHS];
  int tid = threadIdx.x;
  int wave = tid >> 6, lane = tid & 63;
  int c = lane * 4;
#pragma unroll
  for (int g = 0; g < NGRAPHS; ++g) lacc[g][tid] = 0.f;
  if (tid < NGRAPHS) lcnt[tid] = 0.f;
  __syncthreads();

  int n0 = blockIdx.x * PBLK + wave * 64;
  if (n0 < N_NODES){
    int n1 = min(n0 + 64, N_NODES);
    int b0 = batch[n0], b1 = batch[n1 - 1];
    float a0 = 0.f, a1 = 0.f, a2 = 0.f, a3 = 0.f;
    if (b0 == b1){                            // wave-uniform fast path
      int i = n0;
      for (; i + 8 <= n1; i += 8){
        uint2 v[8];
#pragma unroll
        for (int j = 0; j < 8; ++j) v[j] = *(const uint2*)(x_bf + (size_t)(i + j) * 256 + c);
#pragma unroll
        for (int j = 0; j < 8; ++j){
          a0 += bflo(v[j].x); a1 += bfhi(v[j].x);
          a2 += bflo(v[j].y); a3 += bfhi(v[j].y);
        }
      }
      for (; i < n1; ++i){
        uint2 v = *(const uint2*)(x_bf + (size_t)i * 256 + c);
        a0 += bflo(v.x); a1 += bfhi(v.x); a2 += bflo(v.y); a3 += bfhi(v.y);
      }
      atomicAdd(&lacc[b0][c + 0], a0); atomicAdd(&lacc[b0][c + 1], a1);
      atomicAdd(&lacc[b0][c + 2], a2); atomicAdd(&lacc[b0][c + 3], a3);
      if (lane == 0) atomicAdd(&lcnt[b0], (float)(n1 - n0));
    } else {                                  // boundary wave (<=15 per launch)
      int cur = b0, cnt = 0;
      for (int i = n0; i < n1; ++i){
        int g = batch[i];
        if (g != cur){
          atomicAdd(&lacc[cur][c + 0], a0); atomicAdd(&lacc[cur][c + 1], a1);
          atomicAdd(&lacc[cur][c + 2], a2); atomicAdd(&lacc[cur][c + 3], a3);
          if (lane == 0) atomicAdd(&lcnt[cur], (float)cnt);
          a0 = a1 = a2 = a3 = 0.f; cnt = 0; cur = g;
        }
        uint2 v = *(const uint2*)(x_bf + (size_t)i * 256 + c);
        a0 += bflo(v.x); a1 += bfhi(v.x); a2 += bflo(v.y); a3 += bfhi(v.y);
        cnt++;
      }
      atomicAdd(&lacc[cur][c + 0], a0); atomicAdd(&lacc[cur][c + 1], a1);
      atomicAdd(&lacc[cur][c + 2], a2); atomicAdd(&lacc[cur][c + 3], a3);
      if (lane == 0) atomicAdd(&lcnt[cur], (float)cnt);
    }
  }
  __syncthreads();

  int base = blockIdx.x * PBLK;
  if (base < N_NODES){
    int gmin = batch[base];
    int gmax = batch[min(base + PBLK, N_NODES) - 1];
    for (int g = gmin; g <= gmax; ++g){
      float v = lacc[g][tid];
      if (v != 0.f) atomicAdd(&pooled[g * 256 + tid], v);
      if (tid == 0 && lcnt[g] > 0.f) atomicAdd(&counts[g], lcnt[g]);
    }
  }
}

__global__ __launch_bounds__(256) void k_head(const float* __restrict__ pooled, const float* __restrict__ counts,
    const float* __restrict__ params, void* __restrict__ out, const int* __restrict__ flag){
  __shared__ float m[256];
  __shared__ float hh[256];
  __shared__ float red[2][4];
  int g = blockIdx.x, tid = threadIdx.x;
  float cnt = fmaxf(counts[g], 1.f);
  m[tid] = pooled[g * 256 + tid] / cnt;
  __syncthreads();
  const float* W1 = params + OFF_WO1;
  float acc = params[OFF_BO1 + tid];
  for (int k = 0; k < 256; ++k) acc = fmaf(m[k], W1[k * 256 + tid], acc);
  acc = fmaxf(acc, 0.f);
  float s = wave_reduce_sum(acc), ss = wave_reduce_sum(acc * acc);
  int wv = tid >> 6, lane = tid & 63;
  if (lane == 0){ red[0][wv] = s; red[1][wv] = ss; }
  __syncthreads();
  float S  = red[0][0] + red[0][1] + red[0][2] + red[0][3];
  float SS = red[1][0] + red[1][1] + red[1][2] + red[1][3];
  float mean = S * (1.f/256.f);
  float var  = SS * (1.f/256.f) - mean * mean;
  float inv  = rsqrtf(var + EPS);
  float hn = (acc - mean) * inv * params[OFF_GO + tid] + params[OFF_BEO + tid];
  hh[tid] = hn;
  __syncthreads();
  if (tid < ZDIM){
    const float* W2 = params + OFF_WO2;
    float o = params[OFF_BO2 + tid];
    for (int k = 0; k < 256; ++k) o = fmaf(hh[k], W2[k * 128 + tid], o);
    if (*flag) ((float*)out)[g * 128 + tid] = o;
    else       ((__hip_bfloat16*)out)[g * 128 + tid] = __float2bfloat16(o);
  }
}

extern "C" void kernel_launch(void* const* d_in, const int* in_sizes, int n_in,
                              void* d_out, int out_size, void* d_ws, size_t ws_size,
                              hipStream_t stream){
  // ---- workspace layout ----
  size_t o = 0;
  auto alloc = [&](size_t bytes)->size_t{ size_t r = o; o = (o + bytes + 255) & ~(size_t)255; return r; };
  size_t off_flag   = alloc(4);
  size_t off_deg    = alloc((size_t)N_NODES * 4);
  size_t off_dinv   = alloc((size_t)N_NODES * 4);
  size_t off_rs     = alloc((size_t)(N_NODES + 1) * 4);
  size_t off_fill   = alloc((size_t)N_NODES * 4);
  size_t off_bsum   = alloc((size_t)NSCANBLK * 4);
  size_t off_boff   = alloc((size_t)NSCANBLK * 4);
  size_t off_csrs   = alloc((size_t)(N_EDGES + N_NODES) * 4);
  size_t off_csrw   = alloc((size_t)(N_EDGES + N_NODES) * 4);
  size_t off_params = alloc((size_t)PARAMS_TOTAL * 4);
  size_t off_x0     = alloc((size_t)N_NODES * HIDDEN * 2);
  size_t off_x1     = alloc((size_t)N_NODES * HIDDEN * 2);
  size_t off_wt     = alloc((size_t)NLAYERS * HIDDEN * HIDDEN * 2);
  size_t off_pool   = alloc((size_t)NGRAPHS * 256 * 4);
  size_t off_cnt    = alloc((size_t)NGRAPHS * 4);
  if (o > ws_size) return;

  char* ws = (char*)d_ws;
  int*    flag     = (int*)(ws + off_flag);
  int*    deg      = (int*)(ws + off_deg);
  float*  dinv     = (float*)(ws + off_dinv);
  int*    row_start= (int*)(ws + off_rs);
  int*    fill     = (int*)(ws + off_fill);
  int*    bsum     = (int*)(ws + off_bsum);
  int*    boff     = (int*)(ws + off_boff);
  int*    csr_src  = (int*)(ws + off_csrs);
  float*  csr_w    = (float*)(ws + off_csrw);
  float*  params   = (float*)(ws + off_params);
  ushort* x0       = (ushort*)(ws + off_x0);
  ushort* x1       = (ushort*)(ws + off_x1);
  ushort* Wt       = (ushort*)(ws + off_wt);
  float*  pooled   = (float*)(ws + off_pool);
  float*  counts   = (float*)(ws + off_cnt);

  const int* edge_src = (const int*)d_in[1];               // edge_index[0]
  const int* edge_dst = (const int*)d_in[1] + N_EDGES;     // edge_index[1]
  const int* batch    = (const int*)d_in[2];

  // ---- fused dtype detect + param convert + Wt build ----
  PrepArgs pa;
  const int srcIdx[14] = {0,3,4,5,6,8,9,10,11,12,13,14,15,16};
  const int ns[14]     = {150000,768,256,256,256,768,768,768,65536,256,256,256,32768,128};
  const int offs[14]   = {OFF_POS,OFF_WIN,OFF_BIN,OFF_GIN,OFF_BEIN,OFF_CONVB,OFF_GNG,OFF_GNB,
                          OFF_WO1,OFF_BO1,OFF_GO,OFF_BEO,OFF_WO2,OFF_BO2};
  for (int i = 0; i < 14; ++i){ pa.src[i] = d_in[srcIdx[i]]; pa.n[i] = ns[i]; pa.off[i] = offs[i]; }
  pa.win = d_in[3]; pa.convw = d_in[7];
  k_prep<<<512, 256, 0, stream>>>(pa, params, Wt, flag);

  // ---- graph preprocessing ----
  k_init<<<(N_NODES + 255) / 256, 256, 0, stream>>>(deg, fill, pooled, counts);
  k_deg<<<(N_EDGES + 255) / 256, 256, 0, stream>>>(edge_dst, deg);
  k_scan1<<<NSCANBLK, 256, 0, stream>>>(deg, row_start, bsum, dinv);
  k_scan2<<<1, 256, 0, stream>>>(bsum, boff, row_start);
  k_scan3<<<NSCANBLK, 256, 0, stream>>>(deg, boff, row_start);
  k_fill<<<(N_EDGES + N_NODES + 255) / 256, 256, 0, stream>>>(edge_src, edge_dst, row_start, fill,
                                                              dinv, csr_src, csr_w);
  // ---- input projection (-> x0) ----
  k_input_proj<<<N_NODES / 4, 256, 0, stream>>>(params, x0);

  // ---- fused GCN layers (ping-pong x0/x1) ----
  int nlb = (N_NODES + LBM - 1) / LBM;
  k_layer<<<nlb, 256, 0, stream>>>(x0, x1, row_start, csr_src, csr_w, Wt + 0 * 65536, params, 0);
  k_layer<<<nlb, 256, 0, stream>>>(x1, x0, row_start, csr_src, csr_w, Wt + 1 * 65536, params, 1);
  k_layer<<<nlb, 256, 0, stream>>>(x0, x1, row_start, csr_src, csr_w, Wt + 2 * 65536, params, 2);

  // ---- pool + head (final state in x1) ----
  k_pool<<<(N_NODES + PBLK - 1) / PBLK, 256, 0, stream>>>(x1, batch, pooled, counts);
  k_head<<<NGRAPHS, 256, 0, stream>>>(pooled, counts, params, d_out, flag);
}

// Round 9
// 362.469 us; speedup vs baseline: 1.5273x; 1.5273x over previous
//
#include <hip/hip_runtime.h>
#include <hip/hip_bf16.h>

#define N_NODES 50000
#define N_EDGES 300000
#define HIDDEN 256
#define ZDIM 128
#define NLAYERS 3
#define NGRAPHS 16
#define EPS 1e-5f
#define NSCANBLK 196   // ceil(50000/256)

// ---- fp32 param region offsets (floats) ----
#define OFF_POS    0
#define OFF_WIN    150000
#define OFF_BIN    150768
#define OFF_GIN    151024
#define OFF_BEIN   151280
#define OFF_CONVB  348144
#define OFF_GNG    348912
#define OFF_GNB    349680
#define OFF_WO1    350448
#define OFF_BO1    415984
#define OFF_GO     416240
#define OFF_BEO    416496
#define OFF_WO2    416752
#define OFF_BO2    449520
#define PARAMS_TOTAL 449648

typedef __attribute__((ext_vector_type(8))) short short8;
typedef __attribute__((ext_vector_type(4))) float floatx4;

__device__ inline float wave_reduce_sum(float v){
#pragma unroll
  for (int off = 32; off; off >>= 1) v += __shfl_xor(v, off);
  return v;
}

__device__ inline ushort f2bf(float f){
  __hip_bfloat16 t = __float2bfloat16(f);
  return *(ushort*)&t;
}
__device__ inline float bflo(unsigned int u){ return __uint_as_float(u << 16); }
__device__ inline float bfhi(unsigned int u){ return __uint_as_float(u & 0xffff0000u); }

__device__ inline void gload_lds16(const void* g, void* l){
  __builtin_amdgcn_global_load_lds((const __attribute__((address_space(1))) void*)g,
                                   (__attribute__((address_space(3))) void*)l, 16, 0, 0);
}

struct PrepArgs { const void* src[14]; int n[14]; int off[14]; const void* win; const void* convw; };

// fused: dtype detect + param convert + Wt build + deg/fill/pooled/counts init
__global__ __launch_bounds__(256) void k_prep(PrepArgs a, float* __restrict__ params,
                                              ushort* __restrict__ Wt, int* __restrict__ flag,
                                              int* __restrict__ deg, int* __restrict__ fill,
                                              float* __restrict__ pooled, float* __restrict__ counts){
  __shared__ int sf;
  int tid = threadIdx.x;
  if (tid == 0) sf = 0;
  __syncthreads();
  const unsigned short* w = (const unsigned short*)a.win;
  for (int i = tid; i < 768; i += 256){
    int e = (w[i] >> 7) & 0xff;            // bf16 exponent field
    if (e >= 148) atomicOr(&sf, 1);        // |v|>=2^20: impossible for real bf16 weights
  }
  __syncthreads();
  const bool isf32 = (sf != 0);
  if (blockIdx.x == 0 && tid == 0) *flag = sf;

  int stride = gridDim.x * blockDim.x;
  int t0 = blockIdx.x * blockDim.x + tid;
  // init side-buffers (self-loop contributes deg=1)
  for (int i = t0; i < N_NODES; i += stride){ deg[i] = 1; fill[i] = 0; }
  for (int i = t0; i < NGRAPHS * 256; i += stride) pooled[i] = 0.f;
  for (int i = t0; i < NGRAPHS; i += stride) counts[i] = 0.f;

  for (int s = 0; s < 14; ++s){
    const void* src = a.src[s];
    int n = a.n[s];
    float* dst = params + a.off[s];
    if (isf32){
      const float* f = (const float*)src;
      for (int i = t0; i < n; i += stride) dst[i] = f[i];
    } else {
      const unsigned short* u = (const unsigned short*)src;
      for (int i = t0; i < n; i += stride) dst[i] = bflo(u[i]);
    }
  }
  // Wt[l][n][k] = conv_W[l][k][n] as bf16, read directly from source
  for (int idx = t0; idx < NLAYERS * 65536; idx += stride){
    int l = idx >> 16, rem = idx & 65535, n = rem >> 8, k = rem & 255;
    int si = l * 65536 + k * 256 + n;
    float v = isf32 ? ((const float*)a.convw)[si] : bflo(((const unsigned short*)a.convw)[si]);
    Wt[idx] = f2bf(v);
  }
}

__global__ void k_deg(const int* __restrict__ dst, int* __restrict__ deg){
  int e = blockIdx.x * blockDim.x + threadIdx.x;
  if (e < N_EDGES) atomicAdd(&deg[dst[e]], 1);
}

// ---- hierarchical exclusive scan of deg -> row_start (+ fused dinv) ----
__global__ __launch_bounds__(256) void k_scan1(const int* __restrict__ deg, int* __restrict__ row_start,
                                               int* __restrict__ bsum, float* __restrict__ dinv){
  __shared__ int sd[256];
  int tid = threadIdx.x;
  int i = blockIdx.x * 256 + tid;
  int v = (i < N_NODES) ? deg[i] : 0;
  if (i < N_NODES) dinv[i] = rsqrtf((float)v);
  sd[tid] = v;
  __syncthreads();
#pragma unroll
  for (int off = 1; off < 256; off <<= 1){
    int t = (tid >= off) ? sd[tid - off] : 0;
    __syncthreads();
    sd[tid] += t;
    __syncthreads();
  }
  if (i < N_NODES) row_start[i] = sd[tid];
  if (tid == 255) bsum[blockIdx.x] = sd[255];
}

__global__ __launch_bounds__(256) void k_scan2(const int* __restrict__ bsum, int* __restrict__ boff,
                                               int* __restrict__ row_start){
  __shared__ int sd[256];
  int tid = threadIdx.x;
  int v = (tid < NSCANBLK) ? bsum[tid] : 0;
  sd[tid] = v;
  __syncthreads();
#pragma unroll
  for (int off = 1; off < 256; off <<= 1){
    int t = (tid >= off) ? sd[tid - off] : 0;
    __syncthreads();
    sd[tid] += t;
    __syncthreads();
  }
  if (tid < NSCANBLK) boff[tid] = sd[tid] - v;   // exclusive
  if (tid == NSCANBLK - 1) row_start[N_NODES] = sd[tid];
}

__global__ __launch_bounds__(256) void k_scan3(const int* __restrict__ deg, const int* __restrict__ boff,
                                               int* __restrict__ row_start){
  int i = blockIdx.x * 256 + threadIdx.x;
  if (i < N_NODES) row_start[i] = row_start[i] + boff[blockIdx.x] - deg[i];
}

// packed CSR: one uint2 {src, w-bits} per entry (one 8B store, one 8B load downstream)
__global__ void k_fill(const int* __restrict__ src, const int* __restrict__ dst,
                       const int* __restrict__ row_start, int* __restrict__ fill,
                       const float* __restrict__ dinv, uint2* __restrict__ csr){
  int t = blockIdx.x * blockDim.x + threadIdx.x;
  if (t >= N_EDGES + N_NODES) return;
  int s, d;
  if (t < N_EDGES){ s = src[t]; d = dst[t]; }
  else            { s = t - N_EDGES; d = s; }      // self loops
  int pos = row_start[d] + atomicAdd(&fill[d], 1);
  uint2 e; e.x = (unsigned)s; e.y = __float_as_uint(dinv[s] * dinv[d]);
  csr[pos] = e;
}

// input projection: Linear(3,256) -> ReLU -> GroupNorm(1,256). one wave per node. bf16 out.
__global__ __launch_bounds__(256) void k_input_proj(const float* __restrict__ params,
                                                    ushort* __restrict__ x_bf){
  int lane = threadIdx.x & 63;
  int node = (blockIdx.x << 2) + (threadIdx.x >> 6);
  if (node >= N_NODES) return;
  const float* pos = params + OFF_POS + node * 3;
  float px = pos[0], py = pos[1], pz = pos[2];
  int c = lane * 4;
  const float* w0 = params + OFF_WIN;
  float v[4];
#pragma unroll
  for (int j = 0; j < 4; ++j){
    float t = params[OFF_BIN + c + j];
    t = fmaf(px, w0[c + j], t);
    t = fmaf(py, w0[256 + c + j], t);
    t = fmaf(pz, w0[512 + c + j], t);
    v[j] = fmaxf(t, 0.f);
  }
  float s  = v[0] + v[1] + v[2] + v[3];
  float ss = v[0]*v[0] + v[1]*v[1] + v[2]*v[2] + v[3]*v[3];
  s = wave_reduce_sum(s); ss = wave_reduce_sum(ss);
  float mean = s * (1.f/256.f);
  float var  = ss * (1.f/256.f) - mean * mean;
  float inv  = rsqrtf(var + EPS);
  float4 o;
  o.x = (v[0]-mean)*inv*params[OFF_GIN+c+0] + params[OFF_BEIN+c+0];
  o.y = (v[1]-mean)*inv*params[OFF_GIN+c+1] + params[OFF_BEIN+c+1];
  o.z = (v[2]-mean)*inv*params[OFF_GIN+c+2] + params[OFF_BEIN+c+2];
  o.w = (v[3]-mean)*inv*params[OFF_GIN+c+3] + params[OFF_BEIN+c+3];
  ushort4 ob = { f2bf(o.x), f2bf(o.y), f2bf(o.z), f2bf(o.w) };
  *(ushort4*)(x_bf + node * 256 + c) = ob;
}

// bf16 MFMA GEMM: Cb(Mx256 bf16) = A(Mx256 bf16) @ Wt^T.  Wt is [n][k].
// 128x128 tile, BK=64, async global_load_lds (16B) staging with XOR granule swizzle.
#define GBM 128
__global__ __launch_bounds__(256) void k_gemm_bf(const ushort* __restrict__ A, const ushort* __restrict__ Bt,
                                                 ushort* __restrict__ Cb, int M){
  __shared__ __align__(16) ushort Sh[2 * GBM * 64];   // As | Bs
  ushort* As = Sh;
  ushort* Bs = Sh + GBM * 64;
  int tid = threadIdx.x;
  int wave = tid >> 6, lane = tid & 63;
  int wr = wave >> 1, wc = wave & 1;
  int row0 = blockIdx.y * GBM;
  int col0 = blockIdx.x * GBM;
  int q = lane >> 4, l15 = lane & 15;
  int srow = lane >> 3;      // row within 8-row staging group
  int sg   = lane & 7;       // destination granule
  floatx4 acc[4][4] = {};
  for (int k0 = 0; k0 < 256; k0 += 64){
    __syncthreads();
#pragma unroll
    for (int t = 0; t < 4; ++t){
      int rg = wave * 4 + t;               // 8-row group 0..15
      int r  = rg * 8 + srow;              // tile row 0..127
      int gs = sg ^ (r & 7);               // swizzled SOURCE granule
      const ushort* ga = A  + (size_t)(row0 + r) * 256 + k0 + gs * 8;  // tail rows: valid ws memory, never stored
      const ushort* gb = Bt + (size_t)(col0 + r) * 256 + k0 + gs * 8;
      gload_lds16(ga, As + rg * 512);
      gload_lds16(gb, Bs + rg * 512);
    }
    __syncthreads();
#pragma unroll
    for (int kk = 0; kk < 64; kk += 32){
      short8 af[4], bfr[4];
#pragma unroll
      for (int i = 0; i < 4; ++i){
        int R = wr * 64 + i * 16 + l15;
        int bg = (kk >> 3) + q;                       // logical granule 0..7
        af[i] = *(const short8*)(As + R * 64 + ((bg ^ (R & 7)) << 3));
      }
#pragma unroll
      for (int j = 0; j < 4; ++j){
        int C = wc * 64 + j * 16 + l15;
        int bg = (kk >> 3) + q;
        bfr[j] = *(const short8*)(Bs + C * 64 + ((bg ^ (C & 7)) << 3));
      }
#pragma unroll
      for (int i = 0; i < 4; ++i)
#pragma unroll
        for (int j = 0; j < 4; ++j)
          acc[i][j] = __builtin_amdgcn_mfma_f32_16x16x32_bf16(af[i], bfr[j], acc[i][j], 0, 0, 0);
    }
  }
#pragma unroll
  for (int i = 0; i < 4; ++i){
#pragma unroll
    for (int r = 0; r < 4; ++r){
      int row = row0 + wr * 64 + i * 16 + q * 4 + r;
      if (row < M){
#pragma unroll
        for (int j = 0; j < 4; ++j){
          int col = col0 + wc * 64 + j * 16 + l15;
          Cb[row * 256 + col] = f2bf(acc[i][j][r]);
        }
      }
    }
  }
}

// aggregate over packed CSR (bf16 h) + bias + GroupNorm + ReLU + residual (bf16 x, in-place).
// one wave per node; 8-wide gather batch for MLP.
__global__ __launch_bounds__(256) void k_agg_norm(const ushort* __restrict__ hb, ushort* __restrict__ x_bf,
    const int* __restrict__ row_start, const uint2* __restrict__ csr,
    const float* __restrict__ params, int layer){
  int lane = threadIdx.x & 63;
  int node = (blockIdx.x << 2) + (threadIdx.x >> 6);
  if (node >= N_NODES) return;
  int c = lane * 4;
  float a0 = 0.f, a1 = 0.f, a2 = 0.f, a3 = 0.f;
  int p0 = row_start[node], p1 = row_start[node + 1];
  int p = p0;
  for (; p + 8 <= p1; p += 8){
    uint2 e[8]; uint2 v[8];
#pragma unroll
    for (int j = 0; j < 8; ++j) e[j] = csr[p + j];
#pragma unroll
    for (int j = 0; j < 8; ++j) v[j] = *(const uint2*)(hb + (size_t)e[j].x * 256 + c);
#pragma unroll
    for (int j = 0; j < 8; ++j){
      float w = __uint_as_float(e[j].y);
      a0 = fmaf(w, bflo(v[j].x), a0); a1 = fmaf(w, bfhi(v[j].x), a1);
      a2 = fmaf(w, bflo(v[j].y), a2); a3 = fmaf(w, bfhi(v[j].y), a3);
    }
  }
  for (; p < p1; ++p){
    uint2 e = csr[p];
    float w = __uint_as_float(e.y);
    uint2 v0 = *(const uint2*)(hb + (size_t)e.x * 256 + c);
    a0 = fmaf(w, bflo(v0.x), a0); a1 = fmaf(w, bfhi(v0.x), a1);
    a2 = fmaf(w, bflo(v0.y), a2); a3 = fmaf(w, bfhi(v0.y), a3);
  }
  const float* cb = params + OFF_CONVB + layer * 256;
  float v[4] = { a0 + cb[c], a1 + cb[c+1], a2 + cb[c+2], a3 + cb[c+3] };
  float s  = v[0] + v[1] + v[2] + v[3];
  float ss = v[0]*v[0] + v[1]*v[1] + v[2]*v[2] + v[3]*v[3];
  s = wave_reduce_sum(s); ss = wave_reduce_sum(ss);
  float mean = s * (1.f/256.f);
  float var  = ss * (1.f/256.f) - mean * mean;
  float inv  = rsqrtf(var + EPS);
  const float* g = params + OFF_GNG + layer * 256;
  const float* b = params + OFF_GNB + layer * 256;
  uint2 xo = *(uint2*)(x_bf + (size_t)node * 256 + c);
  float o0 = fmaxf((v[0]-mean)*inv*g[c+0] + b[c+0], 0.f) + bflo(xo.x);
  float o1 = fmaxf((v[1]-mean)*inv*g[c+1] + b[c+1], 0.f) + bfhi(xo.x);
  float o2 = fmaxf((v[2]-mean)*inv*g[c+2] + b[c+2], 0.f) + bflo(xo.y);
  float o3 = fmaxf((v[3]-mean)*inv*g[c+3] + b[c+3], 0.f) + bfhi(xo.y);
  ushort4 ob = { f2bf(o0), f2bf(o1), f2bf(o2), f2bf(o3) };
  *(ushort4*)(x_bf + (size_t)node * 256 + c) = ob;
}

// global mean pool: 196 blocks x 256 nodes; wave owns 64 nodes, 8-deep load unroll;
// LDS [16][256] block accumulator; one global-atomic row flush per graph present in block.
#define PBLK 256
__global__ __launch_bounds__(256) void k_pool(const ushort* __restrict__ x_bf, const int* __restrict__ batch,
                                              float* __restrict__ pooled, float* __restrict__ counts){
  __shared__ float lacc[NGRAPHS][256];
  __shared__ float lcnt[NGRAPHS];
  int tid = threadIdx.x;
  int wave = tid >> 6, lane = tid & 63;
  int c = lane * 4;
#pragma unroll
  for (int g = 0; g < NGRAPHS; ++g) lacc[g][tid] = 0.f;
  if (tid < NGRAPHS) lcnt[tid] = 0.f;
  __syncthreads();

  int n0 = blockIdx.x * PBLK + wave * 64;
  if (n0 < N_NODES){
    int n1 = min(n0 + 64, N_NODES);
    int b0 = batch[n0], b1 = batch[n1 - 1];
    float a0 = 0.f, a1 = 0.f, a2 = 0.f, a3 = 0.f;
    if (b0 == b1){                            // wave-uniform fast path
      int i = n0;
      for (; i + 8 <= n1; i += 8){
        uint2 v[8];
#pragma unroll
        for (int j = 0; j < 8; ++j) v[j] = *(const uint2*)(x_bf + (size_t)(i + j) * 256 + c);
#pragma unroll
        for (int j = 0; j < 8; ++j){
          a0 += bflo(v[j].x); a1 += bfhi(v[j].x);
          a2 += bflo(v[j].y); a3 += bfhi(v[j].y);
        }
      }
      for (; i < n1; ++i){
        uint2 v = *(const uint2*)(x_bf + (size_t)i * 256 + c);
        a0 += bflo(v.x); a1 += bfhi(v.x); a2 += bflo(v.y); a3 += bfhi(v.y);
      }
      atomicAdd(&lacc[b0][c + 0], a0); atomicAdd(&lacc[b0][c + 1], a1);
      atomicAdd(&lacc[b0][c + 2], a2); atomicAdd(&lacc[b0][c + 3], a3);
      if (lane == 0) atomicAdd(&lcnt[b0], (float)(n1 - n0));
    } else {                                  // boundary wave (<=15 per launch)
      int cur = b0, cnt = 0;
      for (int i = n0; i < n1; ++i){
        int g = batch[i];
        if (g != cur){
          atomicAdd(&lacc[cur][c + 0], a0); atomicAdd(&lacc[cur][c + 1], a1);
          atomicAdd(&lacc[cur][c + 2], a2); atomicAdd(&lacc[cur][c + 3], a3);
          if (lane == 0) atomicAdd(&lcnt[cur], (float)cnt);
          a0 = a1 = a2 = a3 = 0.f; cnt = 0; cur = g;
        }
        uint2 v = *(const uint2*)(x_bf + (size_t)i * 256 + c);
        a0 += bflo(v.x); a1 += bfhi(v.x); a2 += bflo(v.y); a3 += bfhi(v.y);
        cnt++;
      }
      atomicAdd(&lacc[cur][c + 0], a0); atomicAdd(&lacc[cur][c + 1], a1);
      atomicAdd(&lacc[cur][c + 2], a2); atomicAdd(&lacc[cur][c + 3], a3);
      if (lane == 0) atomicAdd(&lcnt[cur], (float)cnt);
    }
  }
  __syncthreads();

  int base = blockIdx.x * PBLK;
  if (base < N_NODES){
    int gmin = batch[base];
    int gmax = batch[min(base + PBLK, N_NODES) - 1];
    for (int g = gmin; g <= gmax; ++g){
      float v = lacc[g][tid];
      if (v != 0.f) atomicAdd(&pooled[g * 256 + tid], v);
      if (tid == 0 && lcnt[g] > 0.f) atomicAdd(&counts[g], lcnt[g]);
    }
  }
}

__global__ __launch_bounds__(256) void k_head(const float* __restrict__ pooled, const float* __restrict__ counts,
    const float* __restrict__ params, void* __restrict__ out, const int* __restrict__ flag){
  __shared__ float m[256];
  __shared__ float hh[256];
  __shared__ float red[2][4];
  int g = blockIdx.x, tid = threadIdx.x;
  float cnt = fmaxf(counts[g], 1.f);
  m[tid] = pooled[g * 256 + tid] / cnt;
  __syncthreads();
  const float* W1 = params + OFF_WO1;
  float acc = params[OFF_BO1 + tid];
  for (int k = 0; k < 256; ++k) acc = fmaf(m[k], W1[k * 256 + tid], acc);
  acc = fmaxf(acc, 0.f);
  float s = wave_reduce_sum(acc), ss = wave_reduce_sum(acc * acc);
  int wv = tid >> 6, lane = tid & 63;
  if (lane == 0){ red[0][wv] = s; red[1][wv] = ss; }
  __syncthreads();
  float S  = red[0][0] + red[0][1] + red[0][2] + red[0][3];
  float SS = red[1][0] + red[1][1] + red[1][2] + red[1][3];
  float mean = S * (1.f/256.f);
  float var  = SS * (1.f/256.f) - mean * mean;
  float inv  = rsqrtf(var + EPS);
  float hn = (acc - mean) * inv * params[OFF_GO + tid] + params[OFF_BEO + tid];
  hh[tid] = hn;
  __syncthreads();
  if (tid < ZDIM){
    const float* W2 = params + OFF_WO2;
    float o = params[OFF_BO2 + tid];
    for (int k = 0; k < 256; ++k) o = fmaf(hh[k], W2[k * 128 + tid], o);
    if (*flag) ((float*)out)[g * 128 + tid] = o;
    else       ((__hip_bfloat16*)out)[g * 128 + tid] = __float2bfloat16(o);
  }
}

extern "C" void kernel_launch(void* const* d_in, const int* in_sizes, int n_in,
                              void* d_out, int out_size, void* d_ws, size_t ws_size,
                              hipStream_t stream){
  // ---- workspace layout ----
  size_t o = 0;
  auto alloc = [&](size_t bytes)->size_t{ size_t r = o; o = (o + bytes + 255) & ~(size_t)255; return r; };
  size_t off_flag   = alloc(4);
  size_t off_deg    = alloc((size_t)N_NODES * 4);
  size_t off_dinv   = alloc((size_t)N_NODES * 4);
  size_t off_rs     = alloc((size_t)(N_NODES + 1) * 4);
  size_t off_fill   = alloc((size_t)N_NODES * 4);
  size_t off_bsum   = alloc((size_t)NSCANBLK * 4);
  size_t off_boff   = alloc((size_t)NSCANBLK * 4);
  size_t off_csr    = alloc((size_t)(N_EDGES + N_NODES) * 8);
  size_t off_params = alloc((size_t)PARAMS_TOTAL * 4);
  size_t off_xbf    = alloc((size_t)N_NODES * HIDDEN * 2);
  size_t off_hbf    = alloc((size_t)N_NODES * HIDDEN * 2);
  size_t off_wt     = alloc((size_t)NLAYERS * HIDDEN * HIDDEN * 2);
  size_t off_pool   = alloc((size_t)NGRAPHS * 256 * 4);
  size_t off_cnt    = alloc((size_t)NGRAPHS * 4);
  if (o > ws_size) return;

  char* ws = (char*)d_ws;
  int*    flag     = (int*)(ws + off_flag);
  int*    deg      = (int*)(ws + off_deg);
  float*  dinv     = (float*)(ws + off_dinv);
  int*    row_start= (int*)(ws + off_rs);
  int*    fill     = (int*)(ws + off_fill);
  int*    bsum     = (int*)(ws + off_bsum);
  int*    boff     = (int*)(ws + off_boff);
  uint2*  csr      = (uint2*)(ws + off_csr);
  float*  params   = (float*)(ws + off_params);
  ushort* x_bf     = (ushort*)(ws + off_xbf);
  ushort* h_bf     = (ushort*)(ws + off_hbf);
  ushort* Wt       = (ushort*)(ws + off_wt);
  float*  pooled   = (float*)(ws + off_pool);
  float*  counts   = (float*)(ws + off_cnt);

  const int* edge_src = (const int*)d_in[1];               // edge_index[0]
  const int* edge_dst = (const int*)d_in[1] + N_EDGES;     // edge_index[1]
  const int* batch    = (const int*)d_in[2];

  // ---- fused dtype detect + param convert + Wt build + buffer init ----
  PrepArgs pa;
  const int srcIdx[14] = {0,3,4,5,6,8,9,10,11,12,13,14,15,16};
  const int ns[14]     = {150000,768,256,256,256,768,768,768,65536,256,256,256,32768,128};
  const int offs[14]   = {OFF_POS,OFF_WIN,OFF_BIN,OFF_GIN,OFF_BEIN,OFF_CONVB,OFF_GNG,OFF_GNB,
                          OFF_WO1,OFF_BO1,OFF_GO,OFF_BEO,OFF_WO2,OFF_BO2};
  for (int i = 0; i < 14; ++i){ pa.src[i] = d_in[srcIdx[i]]; pa.n[i] = ns[i]; pa.off[i] = offs[i]; }
  pa.win = d_in[3]; pa.convw = d_in[7];
  k_prep<<<512, 256, 0, stream>>>(pa, params, Wt, flag, deg, fill, pooled, counts);

  // ---- graph preprocessing ----
  k_deg<<<(N_EDGES + 255) / 256, 256, 0, stream>>>(edge_dst, deg);
  k_scan1<<<NSCANBLK, 256, 0, stream>>>(deg, row_start, bsum, dinv);
  k_scan2<<<1, 256, 0, stream>>>(bsum, boff, row_start);
  k_scan3<<<NSCANBLK, 256, 0, stream>>>(deg, boff, row_start);
  k_fill<<<(N_EDGES + N_NODES + 255) / 256, 256, 0, stream>>>(edge_src, edge_dst, row_start, fill,
                                                              dinv, csr);
  // ---- input projection ----
  k_input_proj<<<N_NODES / 4, 256, 0, stream>>>(params, x_bf);

  // ---- GCN layers (split: MFMA GEMM + gather/norm) ----
  dim3 ggrid(2, (N_NODES + GBM - 1) / GBM);
  for (int l = 0; l < NLAYERS; ++l){
    k_gemm_bf<<<ggrid, 256, 0, stream>>>(x_bf, Wt + l * 65536, h_bf, N_NODES);
    k_agg_norm<<<N_NODES / 4, 256, 0, stream>>>(h_bf, x_bf, row_start, csr, params, l);
  }

  // ---- pool + head ----
  k_pool<<<(N_NODES + PBLK - 1) / PBLK, 256, 0, stream>>>(x_bf, batch, pooled, counts);
  k_head<<<NGRAPHS, 256, 0, stream>>>(pooled, counts, params, d_out, flag);
}

// Round 10
// 350.793 us; speedup vs baseline: 1.5781x; 1.0333x over previous
//
#include <hip/hip_runtime.h>
#include <hip/hip_bf16.h>

#define N_NODES 50000
#define N_EDGES 300000
#define HIDDEN 256
#define ZDIM 128
#define NLAYERS 3
#define NGRAPHS 16
#define EPS 1e-5f
#define NSCANBLK 196   // ceil(50000/256)

// ---- fp32 param region offsets (floats) ----
#define OFF_POS    0
#define OFF_WIN    150000
#define OFF_BIN    150768
#define OFF_GIN    151024
#define OFF_BEIN   151280
#define OFF_CONVB  348144
#define OFF_GNG    348912
#define OFF_GNB    349680
#define OFF_WO1    350448
#define OFF_BO1    415984
#define OFF_GO     416240
#define OFF_BEO    416496
#define OFF_WO2    416752
#define OFF_BO2    449520
#define PARAMS_TOTAL 449648

typedef __attribute__((ext_vector_type(8))) short short8;
typedef __attribute__((ext_vector_type(4))) float floatx4;

__device__ inline float wave_reduce_sum(float v){
#pragma unroll
  for (int off = 32; off; off >>= 1) v += __shfl_xor(v, off);
  return v;
}

__device__ inline ushort f2bf(float f){
  __hip_bfloat16 t = __float2bfloat16(f);
  return *(ushort*)&t;
}
__device__ inline float bflo(unsigned int u){ return __uint_as_float(u << 16); }
__device__ inline float bfhi(unsigned int u){ return __uint_as_float(u & 0xffff0000u); }

__device__ inline void gload_lds16(const void* g, void* l){
  __builtin_amdgcn_global_load_lds((const __attribute__((address_space(1))) void*)g,
                                   (__attribute__((address_space(3))) void*)l, 16, 0, 0);
}

__device__ inline void acc8(float* a, float w, uint4 v){
  a[0] = fmaf(w, bflo(v.x), a[0]); a[1] = fmaf(w, bfhi(v.x), a[1]);
  a[2] = fmaf(w, bflo(v.y), a[2]); a[3] = fmaf(w, bfhi(v.y), a[3]);
  a[4] = fmaf(w, bflo(v.z), a[4]); a[5] = fmaf(w, bfhi(v.z), a[5]);
  a[6] = fmaf(w, bflo(v.w), a[6]); a[7] = fmaf(w, bfhi(v.w), a[7]);
}

struct PrepArgs { const void* src[14]; int n[14]; int off[14]; const void* win; const void* convw; };

// fused: dtype detect + param convert + Wt build + deg/fill/pooled/counts init
__global__ __launch_bounds__(256) void k_prep(PrepArgs a, float* __restrict__ params,
                                              ushort* __restrict__ Wt, int* __restrict__ flag,
                                              int* __restrict__ deg, int* __restrict__ fill,
                                              float* __restrict__ pooled, float* __restrict__ counts){
  __shared__ int sf;
  int tid = threadIdx.x;
  if (tid == 0) sf = 0;
  __syncthreads();
  const unsigned short* w = (const unsigned short*)a.win;
  for (int i = tid; i < 768; i += 256){
    int e = (w[i] >> 7) & 0xff;            // bf16 exponent field
    if (e >= 148) atomicOr(&sf, 1);        // |v|>=2^20: impossible for real bf16 weights
  }
  __syncthreads();
  const bool isf32 = (sf != 0);
  if (blockIdx.x == 0 && tid == 0) *flag = sf;

  int stride = gridDim.x * blockDim.x;
  int t0 = blockIdx.x * blockDim.x + tid;
  // init side-buffers (self-loop contributes deg=1)
  for (int i = t0; i < N_NODES; i += stride){ deg[i] = 1; fill[i] = 0; }
  for (int i = t0; i < NGRAPHS * 256; i += stride) pooled[i] = 0.f;
  for (int i = t0; i < NGRAPHS; i += stride) counts[i] = 0.f;

  for (int s = 0; s < 14; ++s){
    const void* src = a.src[s];
    int n = a.n[s];
    float* dst = params + a.off[s];
    if (isf32){
      const float* f = (const float*)src;
      for (int i = t0; i < n; i += stride) dst[i] = f[i];
    } else {
      const unsigned short* u = (const unsigned short*)src;
      for (int i = t0; i < n; i += stride) dst[i] = bflo(u[i]);
    }
  }
  // Wt[l][n][k] = conv_W[l][k][n] as bf16, read directly from source
  for (int idx = t0; idx < NLAYERS * 65536; idx += stride){
    int l = idx >> 16, rem = idx & 65535, n = rem >> 8, k = rem & 255;
    int si = l * 65536 + k * 256 + n;
    float v = isf32 ? ((const float*)a.convw)[si] : bflo(((const unsigned short*)a.convw)[si]);
    Wt[idx] = f2bf(v);
  }
}

__global__ void k_deg(const int* __restrict__ dst, int* __restrict__ deg){
  int e = blockIdx.x * blockDim.x + threadIdx.x;
  if (e < N_EDGES) atomicAdd(&deg[dst[e]], 1);
}

// ---- hierarchical exclusive scan of deg -> row_start (+ fused dinv) ----
__global__ __launch_bounds__(256) void k_scan1(const int* __restrict__ deg, int* __restrict__ row_start,
                                               int* __restrict__ bsum, float* __restrict__ dinv){
  __shared__ int sd[256];
  int tid = threadIdx.x;
  int i = blockIdx.x * 256 + tid;
  int v = (i < N_NODES) ? deg[i] : 0;
  if (i < N_NODES) dinv[i] = rsqrtf((float)v);
  sd[tid] = v;
  __syncthreads();
#pragma unroll
  for (int off = 1; off < 256; off <<= 1){
    int t = (tid >= off) ? sd[tid - off] : 0;
    __syncthreads();
    sd[tid] += t;
    __syncthreads();
  }
  if (i < N_NODES) row_start[i] = sd[tid];
  if (tid == 255) bsum[blockIdx.x] = sd[255];
}

__global__ __launch_bounds__(256) void k_scan2(const int* __restrict__ bsum, int* __restrict__ boff,
                                               int* __restrict__ row_start){
  __shared__ int sd[256];
  int tid = threadIdx.x;
  int v = (tid < NSCANBLK) ? bsum[tid] : 0;
  sd[tid] = v;
  __syncthreads();
#pragma unroll
  for (int off = 1; off < 256; off <<= 1){
    int t = (tid >= off) ? sd[tid - off] : 0;
    __syncthreads();
    sd[tid] += t;
    __syncthreads();
  }
  if (tid < NSCANBLK) boff[tid] = sd[tid] - v;   // exclusive
  if (tid == NSCANBLK - 1) row_start[N_NODES] = sd[tid];
}

__global__ __launch_bounds__(256) void k_scan3(const int* __restrict__ deg, const int* __restrict__ boff,
                                               int* __restrict__ row_start){
  int i = blockIdx.x * 256 + threadIdx.x;
  if (i < N_NODES) row_start[i] = row_start[i] + boff[blockIdx.x] - deg[i];
}

// packed CSR: one uint2 {src, w-bits} per entry
__global__ void k_fill(const int* __restrict__ src, const int* __restrict__ dst,
                       const int* __restrict__ row_start, int* __restrict__ fill,
                       const float* __restrict__ dinv, uint2* __restrict__ csr){
  int t = blockIdx.x * blockDim.x + threadIdx.x;
  if (t >= N_EDGES + N_NODES) return;
  int s, d;
  if (t < N_EDGES){ s = src[t]; d = dst[t]; }
  else            { s = t - N_EDGES; d = s; }      // self loops
  int pos = row_start[d] + atomicAdd(&fill[d], 1);
  uint2 e; e.x = (unsigned)s; e.y = __float_as_uint(dinv[s] * dinv[d]);
  csr[pos] = e;
}

// input projection: Linear(3,256) -> ReLU -> GroupNorm(1,256). one wave per node. bf16 out.
__global__ __launch_bounds__(256) void k_input_proj(const float* __restrict__ params,
                                                    ushort* __restrict__ x_bf){
  int lane = threadIdx.x & 63;
  int node = (blockIdx.x << 2) + (threadIdx.x >> 6);
  if (node >= N_NODES) return;
  const float* pos = params + OFF_POS + node * 3;
  float px = pos[0], py = pos[1], pz = pos[2];
  int c = lane * 4;
  const float* w0 = params + OFF_WIN;
  float v[4];
#pragma unroll
  for (int j = 0; j < 4; ++j){
    float t = params[OFF_BIN + c + j];
    t = fmaf(px, w0[c + j], t);
    t = fmaf(py, w0[256 + c + j], t);
    t = fmaf(pz, w0[512 + c + j], t);
    v[j] = fmaxf(t, 0.f);
  }
  float s  = v[0] + v[1] + v[2] + v[3];
  float ss = v[0]*v[0] + v[1]*v[1] + v[2]*v[2] + v[3]*v[3];
  s = wave_reduce_sum(s); ss = wave_reduce_sum(ss);
  float mean = s * (1.f/256.f);
  float var  = ss * (1.f/256.f) - mean * mean;
  float inv  = rsqrtf(var + EPS);
  float4 o;
  o.x = (v[0]-mean)*inv*params[OFF_GIN+c+0] + params[OFF_BEIN+c+0];
  o.y = (v[1]-mean)*inv*params[OFF_GIN+c+1] + params[OFF_BEIN+c+1];
  o.z = (v[2]-mean)*inv*params[OFF_GIN+c+2] + params[OFF_BEIN+c+2];
  o.w = (v[3]-mean)*inv*params[OFF_GIN+c+3] + params[OFF_BEIN+c+3];
  ushort4 ob = { f2bf(o.x), f2bf(o.y), f2bf(o.z), f2bf(o.w) };
  *(ushort4*)(x_bf + node * 256 + c) = ob;
}

// bf16 MFMA GEMM: Cb(Mx256 bf16) = A(Mx256 bf16) @ Wt^T.  Wt is [n][k].
// 128x128 tile, BK=64, async global_load_lds (16B) staging with XOR granule swizzle.
#define GBM 128
__global__ __launch_bounds__(256) void k_gemm_bf(const ushort* __restrict__ A, const ushort* __restrict__ Bt,
                                                 ushort* __restrict__ Cb, int M){
  __shared__ __align__(16) ushort Sh[2 * GBM * 64];   // As | Bs
  ushort* As = Sh;
  ushort* Bs = Sh + GBM * 64;
  int tid = threadIdx.x;
  int wave = tid >> 6, lane = tid & 63;
  int wr = wave >> 1, wc = wave & 1;
  int row0 = blockIdx.y * GBM;
  int col0 = blockIdx.x * GBM;
  int q = lane >> 4, l15 = lane & 15;
  int srow = lane >> 3;      // row within 8-row staging group
  int sg   = lane & 7;       // destination granule
  floatx4 acc[4][4] = {};
  for (int k0 = 0; k0 < 256; k0 += 64){
    __syncthreads();
#pragma unroll
    for (int t = 0; t < 4; ++t){
      int rg = wave * 4 + t;               // 8-row group 0..15
      int r  = rg * 8 + srow;              // tile row 0..127
      int gs = sg ^ (r & 7);               // swizzled SOURCE granule
      const ushort* ga = A  + (size_t)(row0 + r) * 256 + k0 + gs * 8;  // tail rows: valid ws memory, never stored
      const ushort* gb = Bt + (size_t)(col0 + r) * 256 + k0 + gs * 8;
      gload_lds16(ga, As + rg * 512);
      gload_lds16(gb, Bs + rg * 512);
    }
    __syncthreads();
#pragma unroll
    for (int kk = 0; kk < 64; kk += 32){
      short8 af[4], bfr[4];
#pragma unroll
      for (int i = 0; i < 4; ++i){
        int R = wr * 64 + i * 16 + l15;
        int bg = (kk >> 3) + q;                       // logical granule 0..7
        af[i] = *(const short8*)(As + R * 64 + ((bg ^ (R & 7)) << 3));
      }
#pragma unroll
      for (int j = 0; j < 4; ++j){
        int C = wc * 64 + j * 16 + l15;
        int bg = (kk >> 3) + q;
        bfr[j] = *(const short8*)(Bs + C * 64 + ((bg ^ (C & 7)) << 3));
      }
#pragma unroll
      for (int i = 0; i < 4; ++i)
#pragma unroll
        for (int j = 0; j < 4; ++j)
          acc[i][j] = __builtin_amdgcn_mfma_f32_16x16x32_bf16(af[i], bfr[j], acc[i][j], 0, 0, 0);
    }
  }
#pragma unroll
  for (int i = 0; i < 4; ++i){
#pragma unroll
    for (int r = 0; r < 4; ++r){
      int row = row0 + wr * 64 + i * 16 + q * 4 + r;
      if (row < M){
#pragma unroll
        for (int j = 0; j < 4; ++j){
          int col = col0 + wc * 64 + j * 16 + l15;
          Cb[row * 256 + col] = f2bf(acc[i][j][r]);
        }
      }
    }
  }
}

// aggregate over packed CSR (bf16 h) + bias + GroupNorm + ReLU + residual (bf16 x, in-place).
// v3: one wave per node; lane covers 8 channels (uint4); half-waves process neighbors
// p and p+1 concurrently; 4-wide unroll = 8 neighbors in flight per wave.
__global__ __launch_bounds__(256) void k_agg_norm(const ushort* __restrict__ hb, ushort* __restrict__ x_bf,
    const int* __restrict__ row_start, const uint2* __restrict__ csr,
    const float* __restrict__ params, int layer){
  int lane = threadIdx.x & 63;
  int node = (blockIdx.x << 2) + (threadIdx.x >> 6);
  if (node >= N_NODES) return;
  int half = lane >> 5;          // 0: neighbors p, 1: neighbors p+1
  int l32 = lane & 31;
  int c = l32 * 8;               // 8 channels per lane
  float a[8] = {};
  int p0 = row_start[node], p1 = row_start[node + 1];
  int p = p0;
  for (; p + 8 <= p1; p += 8){
    uint2 e0 = csr[p + 0 + half];
    uint2 e1 = csr[p + 2 + half];
    uint2 e2 = csr[p + 4 + half];
    uint2 e3 = csr[p + 6 + half];
    uint4 v0 = *(const uint4*)(hb + (size_t)e0.x * 256 + c);
    uint4 v1 = *(const uint4*)(hb + (size_t)e1.x * 256 + c);
    uint4 v2 = *(const uint4*)(hb + (size_t)e2.x * 256 + c);
    uint4 v3 = *(const uint4*)(hb + (size_t)e3.x * 256 + c);
    acc8(a, __uint_as_float(e0.y), v0);
    acc8(a, __uint_as_float(e1.y), v1);
    acc8(a, __uint_as_float(e2.y), v2);
    acc8(a, __uint_as_float(e3.y), v3);
  }
  for (; p < p1; p += 2){
    int pp = p + half;
    if (pp < p1){
      uint2 e = csr[pp];
      uint4 v = *(const uint4*)(hb + (size_t)e.x * 256 + c);
      acc8(a, __uint_as_float(e.y), v);
    }
  }
  // combine the two half-wave neighbor streams: lanes i and i+32 now hold identical sums
#pragma unroll
  for (int j = 0; j < 8; ++j) a[j] += __shfl_xor(a[j], 32);

  const float* cb = params + OFF_CONVB + layer * 256;
  float v8[8];
  float s = 0.f, ss = 0.f;
#pragma unroll
  for (int j = 0; j < 8; ++j){
    float t = a[j] + cb[c + j];
    v8[j] = t; s += t; ss += t * t;
  }
  // 64-lane reduce counts each channel exactly twice -> scale by 0.5 (exact)
  s  = wave_reduce_sum(s)  * 0.5f;
  ss = wave_reduce_sum(ss) * 0.5f;
  float mean = s * (1.f/256.f);
  float var  = ss * (1.f/256.f) - mean * mean;
  float inv  = rsqrtf(var + EPS);
  if (half == 0){
    const float* g = params + OFF_GNG + layer * 256;
    const float* b = params + OFF_GNB + layer * 256;
    uint4 xo = *(const uint4*)(x_bf + (size_t)node * 256 + c);
    float xr[8] = { bflo(xo.x), bfhi(xo.x), bflo(xo.y), bfhi(xo.y),
                    bflo(xo.z), bfhi(xo.z), bflo(xo.w), bfhi(xo.w) };
    short8 ob;
#pragma unroll
    for (int j = 0; j < 8; ++j){
      float o = fmaxf((v8[j] - mean) * inv * g[c + j] + b[c + j], 0.f) + xr[j];
      ob[j] = (short)f2bf(o);
    }
    *(short8*)(x_bf + (size_t)node * 256 + c) = ob;
  }
}

// global mean pool: 196 blocks x 256 nodes; wave owns 64 nodes, 8-deep load unroll;
// LDS [16][256] block accumulator; one global-atomic row flush per graph present in block.
#define PBLK 256
__global__ __launch_bounds__(256) void k_pool(const ushort* __restrict__ x_bf, const int* __restrict__ batch,
                                              float* __restrict__ pooled, float* __restrict__ counts){
  __shared__ float lacc[NGRAPHS][256];
  __shared__ float lcnt[NGRAPHS];
  int tid = threadIdx.x;
  int wave = tid >> 6, lane = tid & 63;
  int c = lane * 4;
#pragma unroll
  for (int g = 0; g < NGRAPHS; ++g) lacc[g][tid] = 0.f;
  if (tid < NGRAPHS) lcnt[tid] = 0.f;
  __syncthreads();

  int n0 = blockIdx.x * PBLK + wave * 64;
  if (n0 < N_NODES){
    int n1 = min(n0 + 64, N_NODES);
    int b0 = batch[n0], b1 = batch[n1 - 1];
    float a0 = 0.f, a1 = 0.f, a2 = 0.f, a3 = 0.f;
    if (b0 == b1){                            // wave-uniform fast path
      int i = n0;
      for (; i + 8 <= n1; i += 8){
        uint2 v[8];
#pragma unroll
        for (int j = 0; j < 8; ++j) v[j] = *(const uint2*)(x_bf + (size_t)(i + j) * 256 + c);
#pragma unroll
        for (int j = 0; j < 8; ++j){
          a0 += bflo(v[j].x); a1 += bfhi(v[j].x);
          a2 += bflo(v[j].y); a3 += bfhi(v[j].y);
        }
      }
      for (; i < n1; ++i){
        uint2 v = *(const uint2*)(x_bf + (size_t)i * 256 + c);
        a0 += bflo(v.x); a1 += bfhi(v.x); a2 += bflo(v.y); a3 += bfhi(v.y);
      }
      atomicAdd(&lacc[b0][c + 0], a0); atomicAdd(&lacc[b0][c + 1], a1);
      atomicAdd(&lacc[b0][c + 2], a2); atomicAdd(&lacc[b0][c + 3], a3);
      if (lane == 0) atomicAdd(&lcnt[b0], (float)(n1 - n0));
    } else {                                  // boundary wave (<=15 per launch)
      int cur = b0, cnt = 0;
      for (int i = n0; i < n1; ++i){
        int g = batch[i];
        if (g != cur){
          atomicAdd(&lacc[cur][c + 0], a0); atomicAdd(&lacc[cur][c + 1], a1);
          atomicAdd(&lacc[cur][c + 2], a2); atomicAdd(&lacc[cur][c + 3], a3);
          if (lane == 0) atomicAdd(&lcnt[cur], (float)cnt);
          a0 = a1 = a2 = a3 = 0.f; cnt = 0; cur = g;
        }
        uint2 v = *(const uint2*)(x_bf + (size_t)i * 256 + c);
        a0 += bflo(v.x); a1 += bfhi(v.x); a2 += bflo(v.y); a3 += bfhi(v.y);
        cnt++;
      }
      atomicAdd(&lacc[cur][c + 0], a0); atomicAdd(&lacc[cur][c + 1], a1);
      atomicAdd(&lacc[cur][c + 2], a2); atomicAdd(&lacc[cur][c + 3], a3);
      if (lane == 0) atomicAdd(&lcnt[cur], (float)cnt);
    }
  }
  __syncthreads();

  int base = blockIdx.x * PBLK;
  if (base < N_NODES){
    int gmin = batch[base];
    int gmax = batch[min(base + PBLK, N_NODES) - 1];
    for (int g = gmin; g <= gmax; ++g){
      float v = lacc[g][tid];
      if (v != 0.f) atomicAdd(&pooled[g * 256 + tid], v);
      if (tid == 0 && lcnt[g] > 0.f) atomicAdd(&counts[g], lcnt[g]);
    }
  }
}

__global__ __launch_bounds__(256) void k_head(const float* __restrict__ pooled, const float* __restrict__ counts,
    const float* __restrict__ params, void* __restrict__ out, const int* __restrict__ flag){
  __shared__ float m[256];
  __shared__ float hh[256];
  __shared__ float red[2][4];
  int g = blockIdx.x, tid = threadIdx.x;
  float cnt = fmaxf(counts[g], 1.f);
  m[tid] = pooled[g * 256 + tid] / cnt;
  __syncthreads();
  const float* W1 = params + OFF_WO1;
  float acc = params[OFF_BO1 + tid];
  for (int k = 0; k < 256; ++k) acc = fmaf(m[k], W1[k * 256 + tid], acc);
  acc = fmaxf(acc, 0.f);
  float s = wave_reduce_sum(acc), ss = wave_reduce_sum(acc * acc);
  int wv = tid >> 6, lane = tid & 63;
  if (lane == 0){ red[0][wv] = s; red[1][wv] = ss; }
  __syncthreads();
  float S  = red[0][0] + red[0][1] + red[0][2] + red[0][3];
  float SS = red[1][0] + red[1][1] + red[1][2] + red[1][3];
  float mean = S * (1.f/256.f);
  float var  = SS * (1.f/256.f) - mean * mean;
  float inv  = rsqrtf(var + EPS);
  float hn = (acc - mean) * inv * params[OFF_GO + tid] + params[OFF_BEO + tid];
  hh[tid] = hn;
  __syncthreads();
  if (tid < ZDIM){
    const float* W2 = params + OFF_WO2;
    float o = params[OFF_BO2 + tid];
    for (int k = 0; k < 256; ++k) o = fmaf(hh[k], W2[k * 128 + tid], o);
    if (*flag) ((float*)out)[g * 128 + tid] = o;
    else       ((__hip_bfloat16*)out)[g * 128 + tid] = __float2bfloat16(o);
  }
}

extern "C" void kernel_launch(void* const* d_in, const int* in_sizes, int n_in,
                              void* d_out, int out_size, void* d_ws, size_t ws_size,
                              hipStream_t stream){
  // ---- workspace layout ----
  size_t o = 0;
  auto alloc = [&](size_t bytes)->size_t{ size_t r = o; o = (o + bytes + 255) & ~(size_t)255; return r; };
  size_t off_flag   = alloc(4);
  size_t off_deg    = alloc((size_t)N_NODES * 4);
  size_t off_dinv   = alloc((size_t)N_NODES * 4);
  size_t off_rs     = alloc((size_t)(N_NODES + 1) * 4);
  size_t off_fill   = alloc((size_t)N_NODES * 4);
  size_t off_bsum   = alloc((size_t)NSCANBLK * 4);
  size_t off_boff   = alloc((size_t)NSCANBLK * 4);
  size_t off_csr    = alloc((size_t)(N_EDGES + N_NODES) * 8);
  size_t off_params = alloc((size_t)PARAMS_TOTAL * 4);
  size_t off_xbf    = alloc((size_t)N_NODES * HIDDEN * 2);
  size_t off_hbf    = alloc((size_t)N_NODES * HIDDEN * 2);
  size_t off_wt     = alloc((size_t)NLAYERS * HIDDEN * HIDDEN * 2);
  size_t off_pool   = alloc((size_t)NGRAPHS * 256 * 4);
  size_t off_cnt    = alloc((size_t)NGRAPHS * 4);
  if (o > ws_size) return;

  char* ws = (char*)d_ws;
  int*    flag     = (int*)(ws + off_flag);
  int*    deg      = (int*)(ws + off_deg);
  float*  dinv     = (float*)(ws + off_dinv);
  int*    row_start= (int*)(ws + off_rs);
  int*    fill     = (int*)(ws + off_fill);
  int*    bsum     = (int*)(ws + off_bsum);
  int*    boff     = (int*)(ws + off_boff);
  uint2*  csr      = (uint2*)(ws + off_csr);
  float*  params   = (float*)(ws + off_params);
  ushort* x_bf     = (ushort*)(ws + off_xbf);
  ushort* h_bf     = (ushort*)(ws + off_hbf);
  ushort* Wt       = (ushort*)(ws + off_wt);
  float*  pooled   = (float*)(ws + off_pool);
  float*  counts   = (float*)(ws + off_cnt);

  const int* edge_src = (const int*)d_in[1];               // edge_index[0]
  const int* edge_dst = (const int*)d_in[1] + N_EDGES;     // edge_index[1]
  const int* batch    = (const int*)d_in[2];

  // ---- fused dtype detect + param convert + Wt build + buffer init ----
  PrepArgs pa;
  const int srcIdx[14] = {0,3,4,5,6,8,9,10,11,12,13,14,15,16};
  const int ns[14]     = {150000,768,256,256,256,768,768,768,65536,256,256,256,32768,128};
  const int offs[14]   = {OFF_POS,OFF_WIN,OFF_BIN,OFF_GIN,OFF_BEIN,OFF_CONVB,OFF_GNG,OFF_GNB,
                          OFF_WO1,OFF_BO1,OFF_GO,OFF_BEO,OFF_WO2,OFF_BO2};
  for (int i = 0; i < 14; ++i){ pa.src[i] = d_in[srcIdx[i]]; pa.n[i] = ns[i]; pa.off[i] = offs[i]; }
  pa.win = d_in[3]; pa.convw = d_in[7];
  k_prep<<<512, 256, 0, stream>>>(pa, params, Wt, flag, deg, fill, pooled, counts);

  // ---- graph preprocessing ----
  k_deg<<<(N_EDGES + 255) / 256, 256, 0, stream>>>(edge_dst, deg);
  k_scan1<<<NSCANBLK, 256, 0, stream>>>(deg, row_start, bsum, dinv);
  k_scan2<<<1, 256, 0, stream>>>(bsum, boff, row_start);
  k_scan3<<<NSCANBLK, 256, 0, stream>>>(deg, boff, row_start);
  k_fill<<<(N_EDGES + N_NODES + 255) / 256, 256, 0, stream>>>(edge_src, edge_dst, row_start, fill,
                                                              dinv, csr);
  // ---- input projection ----
  k_input_proj<<<N_NODES / 4, 256, 0, stream>>>(params, x_bf);

  // ---- GCN layers (split: MFMA GEMM + gather/norm) ----
  dim3 ggrid(2, (N_NODES + GBM - 1) / GBM);
  for (int l = 0; l < NLAYERS; ++l){
    k_gemm_bf<<<ggrid, 256, 0, stream>>>(x_bf, Wt + l * 65536, h_bf, N_NODES);
    k_agg_norm<<<N_NODES / 4, 256, 0, stream>>>(h_bf, x_bf, row_start, csr, params, l);
  }

  // ---- pool + head ----
  k_pool<<<(N_NODES + PBLK - 1) / PBLK, 256, 0, stream>>>(x_bf, batch, pooled, counts);
  k_head<<<NGRAPHS, 256, 0, stream>>>(pooled, counts, params, d_out, flag);
}

// Round 11
// 345.356 us; speedup vs baseline: 1.6030x; 1.0157x over previous
//
#include <hip/hip_runtime.h>
#include <hip/hip_bf16.h>

#define N_NODES 50000
#define N_EDGES 300000
#define HIDDEN 256
#define ZDIM 128
#define NLAYERS 3
#define NGRAPHS 16
#define EPS 1e-5f
#define NSCANBLK 196   // ceil(50000/256)
#define FILLB 1368     // ceil((N_EDGES+N_NODES)/256)

// ---- fp32 param region offsets (floats) ----
#define OFF_POS    0
#define OFF_WIN    150000
#define OFF_BIN    150768
#define OFF_GIN    151024
#define OFF_BEIN   151280
#define OFF_CONVB  348144
#define OFF_GNG    348912
#define OFF_GNB    349680
#define OFF_WO1    350448
#define OFF_BO1    415984
#define OFF_GO     416240
#define OFF_BEO    416496
#define OFF_WO2    416752
#define OFF_BO2    449520
#define PARAMS_TOTAL 449648

typedef __attribute__((ext_vector_type(8))) short short8;
typedef __attribute__((ext_vector_type(4))) float floatx4;

__device__ inline float wave_reduce_sum(float v){
#pragma unroll
  for (int off = 32; off; off >>= 1) v += __shfl_xor(v, off);
  return v;
}

__device__ inline ushort f2bf(float f){
  __hip_bfloat16 t = __float2bfloat16(f);
  return *(ushort*)&t;
}
__device__ inline float bflo(unsigned int u){ return __uint_as_float(u << 16); }
__device__ inline float bfhi(unsigned int u){ return __uint_as_float(u & 0xffff0000u); }

__device__ inline void gload_lds16(const void* g, void* l){
  __builtin_amdgcn_global_load_lds((const __attribute__((address_space(1))) void*)g,
                                   (__attribute__((address_space(3))) void*)l, 16, 0, 0);
}

__device__ inline void acc8(float* a, float w, uint4 v){
  a[0] = fmaf(w, bflo(v.x), a[0]); a[1] = fmaf(w, bfhi(v.x), a[1]);
  a[2] = fmaf(w, bflo(v.y), a[2]); a[3] = fmaf(w, bfhi(v.y), a[3]);
  a[4] = fmaf(w, bflo(v.z), a[4]); a[5] = fmaf(w, bfhi(v.z), a[5]);
  a[6] = fmaf(w, bflo(v.w), a[6]); a[7] = fmaf(w, bfhi(v.w), a[7]);
}

struct PrepArgs { const void* src[14]; int n[14]; int off[14]; const void* win; const void* convw; };

// fused: dtype detect + param convert + coalesced Wt build (blocks 0..47) + buffer init
__global__ __launch_bounds__(256) void k_prep(PrepArgs a, float* __restrict__ params,
                                              ushort* __restrict__ Wt, int* __restrict__ flag,
                                              int* __restrict__ deg, int* __restrict__ fill,
                                              float* __restrict__ pooled, float* __restrict__ counts){
  __shared__ int sf;
  __shared__ ushort tile[64][72];     // 64x64 transpose tile, padded
  int tid = threadIdx.x;
  if (tid == 0) sf = 0;
  __syncthreads();
  const unsigned short* w = (const unsigned short*)a.win;
  for (int i = tid; i < 768; i += 256){
    int e = (w[i] >> 7) & 0xff;            // bf16 exponent field
    if (e >= 148) atomicOr(&sf, 1);        // |v|>=2^20: impossible for real bf16 weights
  }
  __syncthreads();
  const bool isf32 = (sf != 0);
  if (blockIdx.x == 0 && tid == 0) *flag = sf;

  // Wt[l][n][k] = conv_W[l][k][n] as bf16 — one 64x64 tile per block, LDS transpose,
  // coalesced reads AND writes. bf16 passthrough is exact; fp32 rounds as before.
  if (blockIdx.x < NLAYERS * 16){
    int t = blockIdx.x;
    int l = t >> 4, tt = t & 15;
    int kr0 = (tt >> 2) * 64, nc0 = (tt & 3) * 64;
    size_t base = (size_t)l * 65536;
    int r = tid >> 2;                 // 0..63
    int seg = (tid & 3) * 16;         // 0,16,32,48
    if (isf32){
      const float* srcp = (const float*)a.convw + base + (size_t)(kr0 + r) * 256 + nc0 + seg;
#pragma unroll
      for (int j = 0; j < 16; ++j) tile[r][seg + j] = f2bf(srcp[j]);
    } else {
      const unsigned short* srcp = (const unsigned short*)a.convw + base + (size_t)(kr0 + r) * 256 + nc0 + seg;
#pragma unroll
      for (int j = 0; j < 16; ++j) tile[r][seg + j] = srcp[j];
    }
    __syncthreads();
    ushort* dst = Wt + base + (size_t)(nc0 + r) * 256 + kr0 + seg;   // r = n here
#pragma unroll
    for (int j = 0; j < 16; ++j) dst[j] = tile[seg + j][r];
  }

  int stride = gridDim.x * blockDim.x;
  int t0 = blockIdx.x * blockDim.x + tid;
  // init side-buffers (self-loop contributes deg=1)
  for (int i = t0; i < N_NODES; i += stride){ deg[i] = 1; fill[i] = 0; }
  for (int i = t0; i < NGRAPHS * 256; i += stride) pooled[i] = 0.f;
  for (int i = t0; i < NGRAPHS; i += stride) counts[i] = 0.f;

  for (int s = 0; s < 14; ++s){
    const void* src = a.src[s];
    int n = a.n[s];
    float* dst = params + a.off[s];
    if (isf32){
      const float* f = (const float*)src;
      for (int i = t0; i < n; i += stride) dst[i] = f[i];
    } else {
      const unsigned short* u = (const unsigned short*)src;
      for (int i = t0; i < n; i += stride) dst[i] = bflo(u[i]);
    }
  }
}

__global__ void k_deg(const int* __restrict__ dst, int* __restrict__ deg){
  int e = blockIdx.x * blockDim.x + threadIdx.x;
  if (e < N_EDGES) atomicAdd(&deg[dst[e]], 1);
}

// ---- hierarchical scan of deg (+ fused dinv) ----
__global__ __launch_bounds__(256) void k_scan1(const int* __restrict__ deg, int* __restrict__ row_start,
                                               int* __restrict__ bsum, float* __restrict__ dinv){
  __shared__ int sd[256];
  int tid = threadIdx.x;
  int i = blockIdx.x * 256 + tid;
  int v = (i < N_NODES) ? deg[i] : 0;
  if (i < N_NODES) dinv[i] = rsqrtf((float)v);
  sd[tid] = v;
  __syncthreads();
#pragma unroll
  for (int off = 1; off < 256; off <<= 1){
    int t = (tid >= off) ? sd[tid - off] : 0;
    __syncthreads();
    sd[tid] += t;
    __syncthreads();
  }
  if (i < N_NODES) row_start[i] = sd[tid];    // inclusive within block
  if (tid == 255) bsum[blockIdx.x] = sd[255];
}

__global__ __launch_bounds__(256) void k_scan2(const int* __restrict__ bsum, int* __restrict__ boff,
                                               int* __restrict__ row_start){
  __shared__ int sd[256];
  int tid = threadIdx.x;
  int v = (tid < NSCANBLK) ? bsum[tid] : 0;
  sd[tid] = v;
  __syncthreads();
#pragma unroll
  for (int off = 1; off < 256; off <<= 1){
    int t = (tid >= off) ? sd[tid - off] : 0;
    __syncthreads();
    sd[tid] += t;
    __syncthreads();
  }
  if (tid < NSCANBLK) boff[tid] = sd[tid] - v;   // exclusive block offset
  if (tid == NSCANBLK - 1) row_start[N_NODES] = sd[tid];
}

// fused: CSR fill (final row offsets computed on the fly; finalized rs2 written by
// self-loop threads) + input projection (blocks >= FILLB).
__global__ __launch_bounds__(256) void k_fillproj(const int* __restrict__ src, const int* __restrict__ dst,
    const int* __restrict__ row_start, const int* __restrict__ boff, const int* __restrict__ deg,
    int* __restrict__ fill, const float* __restrict__ dinv, uint2* __restrict__ csr,
    int* __restrict__ rs2, const float* __restrict__ params, ushort* __restrict__ x_bf){
  int b = blockIdx.x, tid = threadIdx.x;
  if (b < FILLB){
    int t = b * 256 + tid;
    if (t == 0) rs2[N_NODES] = row_start[N_NODES];
    if (t < N_EDGES + N_NODES){
      int s, d;
      if (t < N_EDGES){ s = src[t]; d = dst[t]; }
      else            { s = t - N_EDGES; d = s; }      // self loops
      int rsf = row_start[d] + boff[d >> 8] - deg[d];  // final exclusive start of node d
      int pos = rsf + atomicAdd(&fill[d], 1);
      uint2 e; e.x = (unsigned)s; e.y = __float_as_uint(dinv[s] * dinv[d]);
      csr[pos] = e;
      if (t >= N_EDGES) rs2[s] = rsf;                  // materialize finalized offsets
    }
    return;
  }
  // ---- input projection: one wave per node ----
  int lane = tid & 63;
  int node = ((b - FILLB) << 2) + (tid >> 6);
  if (node >= N_NODES) return;
  const float* pos = params + OFF_POS + node * 3;
  float px = pos[0], py = pos[1], pz = pos[2];
  int c = lane * 4;
  const float* w0 = params + OFF_WIN;
  float v[4];
#pragma unroll
  for (int j = 0; j < 4; ++j){
    float t = params[OFF_BIN + c + j];
    t = fmaf(px, w0[c + j], t);
    t = fmaf(py, w0[256 + c + j], t);
    t = fmaf(pz, w0[512 + c + j], t);
    v[j] = fmaxf(t, 0.f);
  }
  float s  = v[0] + v[1] + v[2] + v[3];
  float ss = v[0]*v[0] + v[1]*v[1] + v[2]*v[2] + v[3]*v[3];
  s = wave_reduce_sum(s); ss = wave_reduce_sum(ss);
  float mean = s * (1.f/256.f);
  float var  = ss * (1.f/256.f) - mean * mean;
  float inv  = rsqrtf(var + EPS);
  float4 o;
  o.x = (v[0]-mean)*inv*params[OFF_GIN+c+0] + params[OFF_BEIN+c+0];
  o.y = (v[1]-mean)*inv*params[OFF_GIN+c+1] + params[OFF_BEIN+c+1];
  o.z = (v[2]-mean)*inv*params[OFF_GIN+c+2] + params[OFF_BEIN+c+2];
  o.w = (v[3]-mean)*inv*params[OFF_GIN+c+3] + params[OFF_BEIN+c+3];
  ushort4 ob = { f2bf(o.x), f2bf(o.y), f2bf(o.z), f2bf(o.w) };
  *(ushort4*)(x_bf + node * 256 + c) = ob;
}

// bf16 MFMA GEMM: Cb(Mx256 bf16) = A(Mx256 bf16) @ Wt^T.  Wt is [n][k].
// 128x128 tile, BK=64, async global_load_lds (16B) staging with XOR granule swizzle.
#define GBM 128
__global__ __launch_bounds__(256) void k_gemm_bf(const ushort* __restrict__ A, const ushort* __restrict__ Bt,
                                                 ushort* __restrict__ Cb, int M){
  __shared__ __align__(16) ushort Sh[2 * GBM * 64];   // As | Bs
  ushort* As = Sh;
  ushort* Bs = Sh + GBM * 64;
  int tid = threadIdx.x;
  int wave = tid >> 6, lane = tid & 63;
  int wr = wave >> 1, wc = wave & 1;
  int row0 = blockIdx.y * GBM;
  int col0 = blockIdx.x * GBM;
  int q = lane >> 4, l15 = lane & 15;
  int srow = lane >> 3;      // row within 8-row staging group
  int sg   = lane & 7;       // destination granule
  floatx4 acc[4][4] = {};
  for (int k0 = 0; k0 < 256; k0 += 64){
    __syncthreads();
#pragma unroll
    for (int t = 0; t < 4; ++t){
      int rg = wave * 4 + t;               // 8-row group 0..15
      int r  = rg * 8 + srow;              // tile row 0..127
      int gs = sg ^ (r & 7);               // swizzled SOURCE granule
      const ushort* ga = A  + (size_t)(row0 + r) * 256 + k0 + gs * 8;  // tail rows: valid ws memory, never stored
      const ushort* gb = Bt + (size_t)(col0 + r) * 256 + k0 + gs * 8;
      gload_lds16(ga, As + rg * 512);
      gload_lds16(gb, Bs + rg * 512);
    }
    __syncthreads();
#pragma unroll
    for (int kk = 0; kk < 64; kk += 32){
      short8 af[4], bfr[4];
#pragma unroll
      for (int i = 0; i < 4; ++i){
        int R = wr * 64 + i * 16 + l15;
        int bg = (kk >> 3) + q;                       // logical granule 0..7
        af[i] = *(const short8*)(As + R * 64 + ((bg ^ (R & 7)) << 3));
      }
#pragma unroll
      for (int j = 0; j < 4; ++j){
        int C = wc * 64 + j * 16 + l15;
        int bg = (kk >> 3) + q;
        bfr[j] = *(const short8*)(Bs + C * 64 + ((bg ^ (C & 7)) << 3));
      }
#pragma unroll
      for (int i = 0; i < 4; ++i)
#pragma unroll
        for (int j = 0; j < 4; ++j)
          acc[i][j] = __builtin_amdgcn_mfma_f32_16x16x32_bf16(af[i], bfr[j], acc[i][j], 0, 0, 0);
    }
  }
#pragma unroll
  for (int i = 0; i < 4; ++i){
#pragma unroll
    for (int r = 0; r < 4; ++r){
      int row = row0 + wr * 64 + i * 16 + q * 4 + r;
      if (row < M){
#pragma unroll
        for (int j = 0; j < 4; ++j){
          int col = col0 + wc * 64 + j * 16 + l15;
          Cb[row * 256 + col] = f2bf(acc[i][j][r]);
        }
      }
    }
  }
}

// aggregate over packed CSR (bf16 h) + bias + GroupNorm + ReLU + residual (bf16 x, in-place).
// one wave per node; lane covers 8 channels (uint4); half-waves process neighbors p/p+1.
__global__ __launch_bounds__(256) void k_agg_norm(const ushort* __restrict__ hb, ushort* __restrict__ x_bf,
    const int* __restrict__ rs2, const uint2* __restrict__ csr,
    const float* __restrict__ params, int layer){
  int lane = threadIdx.x & 63;
  int node = (blockIdx.x << 2) + (threadIdx.x >> 6);
  if (node >= N_NODES) return;
  int half = lane >> 5;
  int l32 = lane & 31;
  int c = l32 * 8;
  float a[8] = {};
  int p0 = rs2[node], p1 = rs2[node + 1];
  int p = p0;
  for (; p + 8 <= p1; p += 8){
    uint2 e0 = csr[p + 0 + half];
    uint2 e1 = csr[p + 2 + half];
    uint2 e2 = csr[p + 4 + half];
    uint2 e3 = csr[p + 6 + half];
    uint4 v0 = *(const uint4*)(hb + (size_t)e0.x * 256 + c);
    uint4 v1 = *(const uint4*)(hb + (size_t)e1.x * 256 + c);
    uint4 v2 = *(const uint4*)(hb + (size_t)e2.x * 256 + c);
    uint4 v3 = *(const uint4*)(hb + (size_t)e3.x * 256 + c);
    acc8(a, __uint_as_float(e0.y), v0);
    acc8(a, __uint_as_float(e1.y), v1);
    acc8(a, __uint_as_float(e2.y), v2);
    acc8(a, __uint_as_float(e3.y), v3);
  }
  for (; p < p1; p += 2){
    int pp = p + half;
    if (pp < p1){
      uint2 e = csr[pp];
      uint4 v = *(const uint4*)(hb + (size_t)e.x * 256 + c);
      acc8(a, __uint_as_float(e.y), v);
    }
  }
#pragma unroll
  for (int j = 0; j < 8; ++j) a[j] += __shfl_xor(a[j], 32);

  const float* cb = params + OFF_CONVB + layer * 256;
  float v8[8];
  float s = 0.f, ss = 0.f;
#pragma unroll
  for (int j = 0; j < 8; ++j){
    float t = a[j] + cb[c + j];
    v8[j] = t; s += t; ss += t * t;
  }
  s  = wave_reduce_sum(s)  * 0.5f;    // each channel counted exactly twice
  ss = wave_reduce_sum(ss) * 0.5f;
  float mean = s * (1.f/256.f);
  float var  = ss * (1.f/256.f) - mean * mean;
  float inv  = rsqrtf(var + EPS);
  if (half == 0){
    const float* g = params + OFF_GNG + layer * 256;
    const float* b = params + OFF_GNB + layer * 256;
    uint4 xo = *(const uint4*)(x_bf + (size_t)node * 256 + c);
    float xr[8] = { bflo(xo.x), bfhi(xo.x), bflo(xo.y), bfhi(xo.y),
                    bflo(xo.z), bfhi(xo.z), bflo(xo.w), bfhi(xo.w) };
    short8 ob;
#pragma unroll
    for (int j = 0; j < 8; ++j){
      float o = fmaxf((v8[j] - mean) * inv * g[c + j] + b[c + j], 0.f) + xr[j];
      ob[j] = (short)f2bf(o);
    }
    *(short8*)(x_bf + (size_t)node * 256 + c) = ob;
  }
}

// global mean pool: LDS [16][256] block accumulator; global-atomic flush per present graph.
#define PBLK 256
__global__ __launch_bounds__(256) void k_pool(const ushort* __restrict__ x_bf, const int* __restrict__ batch,
                                              float* __restrict__ pooled, float* __restrict__ counts){
  __shared__ float lacc[NGRAPHS][256];
  __shared__ float lcnt[NGRAPHS];
  int tid = threadIdx.x;
  int wave = tid >> 6, lane = tid & 63;
  int c = lane * 4;
#pragma unroll
  for (int g = 0; g < NGRAPHS; ++g) lacc[g][tid] = 0.f;
  if (tid < NGRAPHS) lcnt[tid] = 0.f;
  __syncthreads();

  int n0 = blockIdx.x * PBLK + wave * 64;
  if (n0 < N_NODES){
    int n1 = min(n0 + 64, N_NODES);
    int b0 = batch[n0], b1 = batch[n1 - 1];
    float a0 = 0.f, a1 = 0.f, a2 = 0.f, a3 = 0.f;
    if (b0 == b1){                            // wave-uniform fast path
      int i = n0;
      for (; i + 8 <= n1; i += 8){
        uint2 v[8];
#pragma unroll
        for (int j = 0; j < 8; ++j) v[j] = *(const uint2*)(x_bf + (size_t)(i + j) * 256 + c);
#pragma unroll
        for (int j = 0; j < 8; ++j){
          a0 += bflo(v[j].x); a1 += bfhi(v[j].x);
          a2 += bflo(v[j].y); a3 += bfhi(v[j].y);
        }
      }
      for (; i < n1; ++i){
        uint2 v = *(const uint2*)(x_bf + (size_t)i * 256 + c);
        a0 += bflo(v.x); a1 += bfhi(v.x); a2 += bflo(v.y); a3 += bfhi(v.y);
      }
      atomicAdd(&lacc[b0][c + 0], a0); atomicAdd(&lacc[b0][c + 1], a1);
      atomicAdd(&lacc[b0][c + 2], a2); atomicAdd(&lacc[b0][c + 3], a3);
      if (lane == 0) atomicAdd(&lcnt[b0], (float)(n1 - n0));
    } else {                                  // boundary wave (<=15 per launch)
      int cur = b0, cnt = 0;
      for (int i = n0; i < n1; ++i){
        int g = batch[i];
        if (g != cur){
          atomicAdd(&lacc[cur][c + 0], a0); atomicAdd(&lacc[cur][c + 1], a1);
          atomicAdd(&lacc[cur][c + 2], a2); atomicAdd(&lacc[cur][c + 3], a3);
          if (lane == 0) atomicAdd(&lcnt[cur], (float)cnt);
          a0 = a1 = a2 = a3 = 0.f; cnt = 0; cur = g;
        }
        uint2 v = *(const uint2*)(x_bf + (size_t)i * 256 + c);
        a0 += bflo(v.x); a1 += bfhi(v.x); a2 += bflo(v.y); a3 += bfhi(v.y);
        cnt++;
      }
      atomicAdd(&lacc[cur][c + 0], a0); atomicAdd(&lacc[cur][c + 1], a1);
      atomicAdd(&lacc[cur][c + 2], a2); atomicAdd(&lacc[cur][c + 3], a3);
      if (lane == 0) atomicAdd(&lcnt[cur], (float)cnt);
    }
  }
  __syncthreads();

  int base = blockIdx.x * PBLK;
  if (base < N_NODES){
    int gmin = batch[base];
    int gmax = batch[min(base + PBLK, N_NODES) - 1];
    for (int g = gmin; g <= gmax; ++g){
      float v = lacc[g][tid];
      if (v != 0.f) atomicAdd(&pooled[g * 256 + tid], v);
      if (tid == 0 && lcnt[g] > 0.f) atomicAdd(&counts[g], lcnt[g]);
    }
  }
}

__global__ __launch_bounds__(256) void k_head(const float* __restrict__ pooled, const float* __restrict__ counts,
    const float* __restrict__ params, void* __restrict__ out, const int* __restrict__ flag){
  __shared__ float m[256];
  __shared__ float hh[256];
  __shared__ float red[2][4];
  int g = blockIdx.x, tid = threadIdx.x;
  float cnt = fmaxf(counts[g], 1.f);
  m[tid] = pooled[g * 256 + tid] / cnt;
  __syncthreads();
  const float* W1 = params + OFF_WO1;
  float acc = params[OFF_BO1 + tid];
  for (int k = 0; k < 256; ++k) acc = fmaf(m[k], W1[k * 256 + tid], acc);
  acc = fmaxf(acc, 0.f);
  float s = wave_reduce_sum(acc), ss = wave_reduce_sum(acc * acc);
  int wv = tid >> 6, lane = tid & 63;
  if (lane == 0){ red[0][wv] = s; red[1][wv] = ss; }
  __syncthreads();
  float S  = red[0][0] + red[0][1] + red[0][2] + red[0][3];
  float SS = red[1][0] + red[1][1] + red[1][2] + red[1][3];
  float mean = S * (1.f/256.f);
  float var  = SS * (1.f/256.f) - mean * mean;
  float inv  = rsqrtf(var + EPS);
  float hn = (acc - mean) * inv * params[OFF_GO + tid] + params[OFF_BEO + tid];
  hh[tid] = hn;
  __syncthreads();
  if (tid < ZDIM){
    const float* W2 = params + OFF_WO2;
    float o = params[OFF_BO2 + tid];
    for (int k = 0; k < 256; ++k) o = fmaf(hh[k], W2[k * 128 + tid], o);
    if (*flag) ((float*)out)[g * 128 + tid] = o;
    else       ((__hip_bfloat16*)out)[g * 128 + tid] = __float2bfloat16(o);
  }
}

extern "C" void kernel_launch(void* const* d_in, const int* in_sizes, int n_in,
                              void* d_out, int out_size, void* d_ws, size_t ws_size,
                              hipStream_t stream){
  // ---- workspace layout ----
  size_t o = 0;
  auto alloc = [&](size_t bytes)->size_t{ size_t r = o; o = (o + bytes + 255) & ~(size_t)255; return r; };
  size_t off_flag   = alloc(4);
  size_t off_deg    = alloc((size_t)N_NODES * 4);
  size_t off_dinv   = alloc((size_t)N_NODES * 4);
  size_t off_rs     = alloc((size_t)(N_NODES + 1) * 4);
  size_t off_rs2    = alloc((size_t)(N_NODES + 1) * 4);
  size_t off_fill   = alloc((size_t)N_NODES * 4);
  size_t off_bsum   = alloc((size_t)NSCANBLK * 4);
  size_t off_boff   = alloc((size_t)NSCANBLK * 4);
  size_t off_csr    = alloc((size_t)(N_EDGES + N_NODES) * 8);
  size_t off_params = alloc((size_t)PARAMS_TOTAL * 4);
  size_t off_xbf    = alloc((size_t)N_NODES * HIDDEN * 2);
  size_t off_hbf    = alloc((size_t)N_NODES * HIDDEN * 2);
  size_t off_wt     = alloc((size_t)NLAYERS * HIDDEN * HIDDEN * 2);
  size_t off_pool   = alloc((size_t)NGRAPHS * 256 * 4);
  size_t off_cnt    = alloc((size_t)NGRAPHS * 4);
  if (o > ws_size) return;

  char* ws = (char*)d_ws;
  int*    flag     = (int*)(ws + off_flag);
  int*    deg      = (int*)(ws + off_deg);
  float*  dinv     = (float*)(ws + off_dinv);
  int*    row_start= (int*)(ws + off_rs);
  int*    rs2      = (int*)(ws + off_rs2);
  int*    fill     = (int*)(ws + off_fill);
  int*    bsum     = (int*)(ws + off_bsum);
  int*    boff     = (int*)(ws + off_boff);
  uint2*  csr      = (uint2*)(ws + off_csr);
  float*  params   = (float*)(ws + off_params);
  ushort* x_bf     = (ushort*)(ws + off_xbf);
  ushort* h_bf     = (ushort*)(ws + off_hbf);
  ushort* Wt       = (ushort*)(ws + off_wt);
  float*  pooled   = (float*)(ws + off_pool);
  float*  counts   = (float*)(ws + off_cnt);

  const int* edge_src = (const int*)d_in[1];               // edge_index[0]
  const int* edge_dst = (const int*)d_in[1] + N_EDGES;     // edge_index[1]
  const int* batch    = (const int*)d_in[2];

  // ---- fused dtype detect + param convert + Wt build + buffer init ----
  PrepArgs pa;
  const int srcIdx[14] = {0,3,4,5,6,8,9,10,11,12,13,14,15,16};
  const int ns[14]     = {150000,768,256,256,256,768,768,768,65536,256,256,256,32768,128};
  const int offs[14]   = {OFF_POS,OFF_WIN,OFF_BIN,OFF_GIN,OFF_BEIN,OFF_CONVB,OFF_GNG,OFF_GNB,
                          OFF_WO1,OFF_BO1,OFF_GO,OFF_BEO,OFF_WO2,OFF_BO2};
  for (int i = 0; i < 14; ++i){ pa.src[i] = d_in[srcIdx[i]]; pa.n[i] = ns[i]; pa.off[i] = offs[i]; }
  pa.win = d_in[3]; pa.convw = d_in[7];
  k_prep<<<512, 256, 0, stream>>>(pa, params, Wt, flag, deg, fill, pooled, counts);

  // ---- graph preprocessing ----
  k_deg<<<(N_EDGES + 255) / 256, 256, 0, stream>>>(edge_dst, deg);
  k_scan1<<<NSCANBLK, 256, 0, stream>>>(deg, row_start, bsum, dinv);
  k_scan2<<<1, 256, 0, stream>>>(bsum, boff, row_start);

  // ---- fused CSR fill (+rs2 finalize) + input projection ----
  int projb = (N_NODES + 3) / 4;
  k_fillproj<<<FILLB + projb, 256, 0, stream>>>(edge_src, edge_dst, row_start, boff, deg, fill,
                                                dinv, csr, rs2, params, x_bf);

  // ---- GCN layers (split: MFMA GEMM + gather/norm) ----
  dim3 ggrid(2, (N_NODES + GBM - 1) / GBM);
  for (int l = 0; l < NLAYERS; ++l){
    k_gemm_bf<<<ggrid, 256, 0, stream>>>(x_bf, Wt + l * 65536, h_bf, N_NODES);
    k_agg_norm<<<N_NODES / 4, 256, 0, stream>>>(h_bf, x_bf, rs2, csr, params, l);
  }

  // ---- pool + head ----
  k_pool<<<(N_NODES + PBLK - 1) / PBLK, 256, 0, stream>>>(x_bf, batch, pooled, counts);
  k_head<<<NGRAPHS, 256, 0, stream>>>(pooled, counts, params, d_out, flag);
}

// Round 12
// 337.482 us; speedup vs baseline: 1.6404x; 1.0233x over previous
//
#include <hip/hip_runtime.h>
#include <hip/hip_bf16.h>

#define N_NODES 50000
#define N_EDGES 300000
#define HIDDEN 256
#define ZDIM 128
#define NLAYERS 3
#define NGRAPHS 16
#define EPS 1e-5f
#define NSCANBLK 196   // ceil(50000/256)
#define FILLB 1368     // ceil((N_EDGES+N_NODES)/256)

// ---- fp32 param region offsets (floats) ----
#define OFF_POS    0
#define OFF_WIN    150000
#define OFF_BIN    150768
#define OFF_GIN    151024
#define OFF_BEIN   151280
#define OFF_CONVB  348144
#define OFF_GNG    348912
#define OFF_GNB    349680
#define OFF_WO1    350448
#define OFF_BO1    415984
#define OFF_GO     416240
#define OFF_BEO    416496
#define OFF_WO2    416752
#define OFF_BO2    449520
#define PARAMS_TOTAL 449648

typedef __attribute__((ext_vector_type(8))) short short8;
typedef __attribute__((ext_vector_type(4))) float floatx4;

__device__ inline float wave_reduce_sum(float v){
#pragma unroll
  for (int off = 32; off; off >>= 1) v += __shfl_xor(v, off);
  return v;
}

__device__ inline ushort f2bf(float f){
  __hip_bfloat16 t = __float2bfloat16(f);
  return *(ushort*)&t;
}
__device__ inline float bflo(unsigned int u){ return __uint_as_float(u << 16); }
__device__ inline float bfhi(unsigned int u){ return __uint_as_float(u & 0xffff0000u); }

__device__ inline void gload_lds16(const void* g, void* l){
  __builtin_amdgcn_global_load_lds((const __attribute__((address_space(1))) void*)g,
                                   (__attribute__((address_space(3))) void*)l, 16, 0, 0);
}

// fp8 e4m3 encode: pack (v,v) and take byte 0 -- immune to pk byte-order convention
__device__ inline unsigned char f2fp8(float v){
  int pk = __builtin_amdgcn_cvt_pk_fp8_f32(v, v, 0, false);
  return (unsigned char)(pk & 0xff);
}

// decode 8 fp8 (one uint2) with explicit byte selects (little-endian: byte k = channel k)
__device__ inline void acc8f(float* a, float w, uint2 v){
  a[0] = fmaf(w, __builtin_amdgcn_cvt_f32_fp8((int)v.x, 0), a[0]);
  a[1] = fmaf(w, __builtin_amdgcn_cvt_f32_fp8((int)v.x, 1), a[1]);
  a[2] = fmaf(w, __builtin_amdgcn_cvt_f32_fp8((int)v.x, 2), a[2]);
  a[3] = fmaf(w, __builtin_amdgcn_cvt_f32_fp8((int)v.x, 3), a[3]);
  a[4] = fmaf(w, __builtin_amdgcn_cvt_f32_fp8((int)v.y, 0), a[4]);
  a[5] = fmaf(w, __builtin_amdgcn_cvt_f32_fp8((int)v.y, 1), a[5]);
  a[6] = fmaf(w, __builtin_amdgcn_cvt_f32_fp8((int)v.y, 2), a[6]);
  a[7] = fmaf(w, __builtin_amdgcn_cvt_f32_fp8((int)v.y, 3), a[7]);
}

struct PrepArgs { const void* src[14]; int n[14]; int off[14]; const void* win; const void* convw; };

// fused: dtype detect + param convert + coalesced Wt build (blocks 0..47) + buffer init
__global__ __launch_bounds__(256) void k_prep(PrepArgs a, float* __restrict__ params,
                                              ushort* __restrict__ Wt, int* __restrict__ flag,
                                              int* __restrict__ deg, int* __restrict__ fill,
                                              float* __restrict__ pooled, float* __restrict__ counts){
  __shared__ int sf;
  __shared__ ushort tile[64][72];     // 64x64 transpose tile, padded
  int tid = threadIdx.x;
  if (tid == 0) sf = 0;
  __syncthreads();
  const unsigned short* w = (const unsigned short*)a.win;
  for (int i = tid; i < 768; i += 256){
    int e = (w[i] >> 7) & 0xff;            // bf16 exponent field
    if (e >= 148) atomicOr(&sf, 1);        // |v|>=2^20: impossible for real bf16 weights
  }
  __syncthreads();
  const bool isf32 = (sf != 0);
  if (blockIdx.x == 0 && tid == 0) *flag = sf;

  // Wt[l][n][k] = conv_W[l][k][n] as bf16 -- one 64x64 tile per block, LDS transpose
  if (blockIdx.x < NLAYERS * 16){
    int t = blockIdx.x;
    int l = t >> 4, tt = t & 15;
    int kr0 = (tt >> 2) * 64, nc0 = (tt & 3) * 64;
    size_t base = (size_t)l * 65536;
    int r = tid >> 2;                 // 0..63
    int seg = (tid & 3) * 16;         // 0,16,32,48
    if (isf32){
      const float* srcp = (const float*)a.convw + base + (size_t)(kr0 + r) * 256 + nc0 + seg;
#pragma unroll
      for (int j = 0; j < 16; ++j) tile[r][seg + j] = f2bf(srcp[j]);
    } else {
      const unsigned short* srcp = (const unsigned short*)a.convw + base + (size_t)(kr0 + r) * 256 + nc0 + seg;
#pragma unroll
      for (int j = 0; j < 16; ++j) tile[r][seg + j] = srcp[j];
    }
    __syncthreads();
    ushort* dst = Wt + base + (size_t)(nc0 + r) * 256 + kr0 + seg;   // r = n here
#pragma unroll
    for (int j = 0; j < 16; ++j) dst[j] = tile[seg + j][r];
  }

  int stride = gridDim.x * blockDim.x;
  int t0 = blockIdx.x * blockDim.x + tid;
  // init side-buffers (self-loop contributes deg=1)
  for (int i = t0; i < N_NODES; i += stride){ deg[i] = 1; fill[i] = 0; }
  for (int i = t0; i < NGRAPHS * 256; i += stride) pooled[i] = 0.f;
  for (int i = t0; i < NGRAPHS; i += stride) counts[i] = 0.f;

  for (int s = 0; s < 14; ++s){
    const void* src = a.src[s];
    int n = a.n[s];
    float* dst = params + a.off[s];
    if (isf32){
      const float* f = (const float*)src;
      for (int i = t0; i < n; i += stride) dst[i] = f[i];
    } else {
      const unsigned short* u = (const unsigned short*)src;
      for (int i = t0; i < n; i += stride) dst[i] = bflo(u[i]);
    }
  }
}

__global__ void k_deg(const int* __restrict__ dst, int* __restrict__ deg){
  int e = blockIdx.x * blockDim.x + threadIdx.x;
  if (e < N_EDGES) atomicAdd(&deg[dst[e]], 1);
}

// ---- hierarchical scan of deg (+ fused dinv) ----
__global__ __launch_bounds__(256) void k_scan1(const int* __restrict__ deg, int* __restrict__ row_start,
                                               int* __restrict__ bsum, float* __restrict__ dinv){
  __shared__ int sd[256];
  int tid = threadIdx.x;
  int i = blockIdx.x * 256 + tid;
  int v = (i < N_NODES) ? deg[i] : 0;
  if (i < N_NODES) dinv[i] = rsqrtf((float)v);
  sd[tid] = v;
  __syncthreads();
#pragma unroll
  for (int off = 1; off < 256; off <<= 1){
    int t = (tid >= off) ? sd[tid - off] : 0;
    __syncthreads();
    sd[tid] += t;
    __syncthreads();
  }
  if (i < N_NODES) row_start[i] = sd[tid];    // inclusive within block
  if (tid == 255) bsum[blockIdx.x] = sd[255];
}

__global__ __launch_bounds__(256) void k_scan2(const int* __restrict__ bsum, int* __restrict__ boff,
                                               int* __restrict__ row_start){
  __shared__ int sd[256];
  int tid = threadIdx.x;
  int v = (tid < NSCANBLK) ? bsum[tid] : 0;
  sd[tid] = v;
  __syncthreads();
#pragma unroll
  for (int off = 1; off < 256; off <<= 1){
    int t = (tid >= off) ? sd[tid - off] : 0;
    __syncthreads();
    sd[tid] += t;
    __syncthreads();
  }
  if (tid < NSCANBLK) boff[tid] = sd[tid] - v;   // exclusive block offset
  if (tid == NSCANBLK - 1) row_start[N_NODES] = sd[tid];
}

// fused: CSR fill (final row offsets on the fly; rs2 finalized by self-loop threads)
// + input projection (blocks >= FILLB).
__global__ __launch_bounds__(256) void k_fillproj(const int* __restrict__ src, const int* __restrict__ dst,
    const int* __restrict__ row_start, const int* __restrict__ boff, const int* __restrict__ deg,
    int* __restrict__ fill, const float* __restrict__ dinv, uint2* __restrict__ csr,
    int* __restrict__ rs2, const float* __restrict__ params, ushort* __restrict__ x_bf){
  int b = blockIdx.x, tid = threadIdx.x;
  if (b < FILLB){
    int t = b * 256 + tid;
    if (t == 0) rs2[N_NODES] = row_start[N_NODES];
    if (t < N_EDGES + N_NODES){
      int s, d;
      if (t < N_EDGES){ s = src[t]; d = dst[t]; }
      else            { s = t - N_EDGES; d = s; }      // self loops
      int rsf = row_start[d] + boff[d >> 8] - deg[d];  // final exclusive start of node d
      int pos = rsf + atomicAdd(&fill[d], 1);
      uint2 e; e.x = (unsigned)s; e.y = __float_as_uint(dinv[s] * dinv[d]);
      csr[pos] = e;
      if (t >= N_EDGES) rs2[s] = rsf;                  // materialize finalized offsets
    }
    return;
  }
  // ---- input projection: one wave per node ----
  int lane = tid & 63;
  int node = ((b - FILLB) << 2) + (tid >> 6);
  if (node >= N_NODES) return;
  const float* pos = params + OFF_POS + node * 3;
  float px = pos[0], py = pos[1], pz = pos[2];
  int c = lane * 4;
  const float* w0 = params + OFF_WIN;
  float v[4];
#pragma unroll
  for (int j = 0; j < 4; ++j){
    float t = params[OFF_BIN + c + j];
    t = fmaf(px, w0[c + j], t);
    t = fmaf(py, w0[256 + c + j], t);
    t = fmaf(pz, w0[512 + c + j], t);
    v[j] = fmaxf(t, 0.f);
  }
  float s  = v[0] + v[1] + v[2] + v[3];
  float ss = v[0]*v[0] + v[1]*v[1] + v[2]*v[2] + v[3]*v[3];
  s = wave_reduce_sum(s); ss = wave_reduce_sum(ss);
  float mean = s * (1.f/256.f);
  float var  = ss * (1.f/256.f) - mean * mean;
  float inv  = rsqrtf(var + EPS);
  float4 o;
  o.x = (v[0]-mean)*inv*params[OFF_GIN+c+0] + params[OFF_BEIN+c+0];
  o.y = (v[1]-mean)*inv*params[OFF_GIN+c+1] + params[OFF_BEIN+c+1];
  o.z = (v[2]-mean)*inv*params[OFF_GIN+c+2] + params[OFF_BEIN+c+2];
  o.w = (v[3]-mean)*inv*params[OFF_GIN+c+3] + params[OFF_BEIN+c+3];
  ushort4 ob = { f2bf(o.x), f2bf(o.y), f2bf(o.z), f2bf(o.w) };
  *(ushort4*)(x_bf + node * 256 + c) = ob;
}

// bf16 MFMA GEMM: C(Mx256, fp8-e4m3 out) = A(Mx256 bf16) @ Wt^T.  Wt is [n][k].
// 128x128 tile, BK=64, async global_load_lds (16B) staging with XOR granule swizzle.
#define GBM 128
__global__ __launch_bounds__(256) void k_gemm_bf(const ushort* __restrict__ A, const ushort* __restrict__ Bt,
                                                 unsigned char* __restrict__ Cb, int M){
  __shared__ __align__(16) ushort Sh[2 * GBM * 64];   // As | Bs
  ushort* As = Sh;
  ushort* Bs = Sh + GBM * 64;
  int tid = threadIdx.x;
  int wave = tid >> 6, lane = tid & 63;
  int wr = wave >> 1, wc = wave & 1;
  int row0 = blockIdx.y * GBM;
  int col0 = blockIdx.x * GBM;
  int q = lane >> 4, l15 = lane & 15;
  int srow = lane >> 3;      // row within 8-row staging group
  int sg   = lane & 7;       // destination granule
  floatx4 acc[4][4] = {};
  for (int k0 = 0; k0 < 256; k0 += 64){
    __syncthreads();
#pragma unroll
    for (int t = 0; t < 4; ++t){
      int rg = wave * 4 + t;               // 8-row group 0..15
      int r  = rg * 8 + srow;              // tile row 0..127
      int gs = sg ^ (r & 7);               // swizzled SOURCE granule
      const ushort* ga = A  + (size_t)(row0 + r) * 256 + k0 + gs * 8;  // tail rows: valid ws memory, never stored
      const ushort* gb = Bt + (size_t)(col0 + r) * 256 + k0 + gs * 8;
      gload_lds16(ga, As + rg * 512);
      gload_lds16(gb, Bs + rg * 512);
    }
    __syncthreads();
#pragma unroll
    for (int kk = 0; kk < 64; kk += 32){
      short8 af[4], bfr[4];
#pragma unroll
      for (int i = 0; i < 4; ++i){
        int R = wr * 64 + i * 16 + l15;
        int bg = (kk >> 3) + q;                       // logical granule 0..7
        af[i] = *(const short8*)(As + R * 64 + ((bg ^ (R & 7)) << 3));
      }
#pragma unroll
      for (int j = 0; j < 4; ++j){
        int C = wc * 64 + j * 16 + l15;
        int bg = (kk >> 3) + q;
        bfr[j] = *(const short8*)(Bs + C * 64 + ((bg ^ (C & 7)) << 3));
      }
#pragma unroll
      for (int i = 0; i < 4; ++i)
#pragma unroll
        for (int j = 0; j < 4; ++j)
          acc[i][j] = __builtin_amdgcn_mfma_f32_16x16x32_bf16(af[i], bfr[j], acc[i][j], 0, 0, 0);
    }
  }
#pragma unroll
  for (int i = 0; i < 4; ++i){
#pragma unroll
    for (int r = 0; r < 4; ++r){
      int row = row0 + wr * 64 + i * 16 + q * 4 + r;
      if (row < M){
#pragma unroll
        for (int j = 0; j < 4; ++j){
          int col = col0 + wc * 64 + j * 16 + l15;
          Cb[(size_t)row * 256 + col] = f2fp8(acc[i][j][r]);
        }
      }
    }
  }
}

// aggregate over packed CSR (fp8 h) + bias + GroupNorm + ReLU + residual (bf16 x, in-place).
// one wave per node; lane covers 8 channels; half-waves process neighbors p/p+1.
__global__ __launch_bounds__(256) void k_agg_norm(const unsigned char* __restrict__ hb,
    ushort* __restrict__ x_bf, const int* __restrict__ rs2, const uint2* __restrict__ csr,
    const float* __restrict__ params, int layer){
  int lane = threadIdx.x & 63;
  int node = (blockIdx.x << 2) + (threadIdx.x >> 6);
  if (node >= N_NODES) return;
  int half = lane >> 5;
  int l32 = lane & 31;
  int c = l32 * 8;
  float a[8] = {};
  int p0 = rs2[node], p1 = rs2[node + 1];
  int p = p0;
  for (; p + 8 <= p1; p += 8){
    uint2 e0 = csr[p + 0 + half];
    uint2 e1 = csr[p + 2 + half];
    uint2 e2 = csr[p + 4 + half];
    uint2 e3 = csr[p + 6 + half];
    uint2 v0 = *(const uint2*)(hb + (size_t)e0.x * 256 + c);
    uint2 v1 = *(const uint2*)(hb + (size_t)e1.x * 256 + c);
    uint2 v2 = *(const uint2*)(hb + (size_t)e2.x * 256 + c);
    uint2 v3 = *(const uint2*)(hb + (size_t)e3.x * 256 + c);
    acc8f(a, __uint_as_float(e0.y), v0);
    acc8f(a, __uint_as_float(e1.y), v1);
    acc8f(a, __uint_as_float(e2.y), v2);
    acc8f(a, __uint_as_float(e3.y), v3);
  }
  for (; p < p1; p += 2){
    int pp = p + half;
    if (pp < p1){
      uint2 e = csr[pp];
      uint2 v = *(const uint2*)(hb + (size_t)e.x * 256 + c);
      acc8f(a, __uint_as_float(e.y), v);
    }
  }
#pragma unroll
  for (int j = 0; j < 8; ++j) a[j] += __shfl_xor(a[j], 32);

  const float* cb = params + OFF_CONVB + layer * 256;
  float v8[8];
  float s = 0.f, ss = 0.f;
#pragma unroll
  for (int j = 0; j < 8; ++j){
    float t = a[j] + cb[c + j];
    v8[j] = t; s += t; ss += t * t;
  }
  s  = wave_reduce_sum(s)  * 0.5f;    // each channel counted exactly twice
  ss = wave_reduce_sum(ss) * 0.5f;
  float mean = s * (1.f/256.f);
  float var  = ss * (1.f/256.f) - mean * mean;
  float inv  = rsqrtf(var + EPS);
  if (half == 0){
    const float* g = params + OFF_GNG + layer * 256;
    const float* b = params + OFF_GNB + layer * 256;
    uint4 xo = *(const uint4*)(x_bf + (size_t)node * 256 + c);
    float xr[8] = { bflo(xo.x), bfhi(xo.x), bflo(xo.y), bfhi(xo.y),
                    bflo(xo.z), bfhi(xo.z), bflo(xo.w), bfhi(xo.w) };
    short8 ob;
#pragma unroll
    for (int j = 0; j < 8; ++j){
      float o = fmaxf((v8[j] - mean) * inv * g[c + j] + b[c + j], 0.f) + xr[j];
      ob[j] = (short)f2bf(o);
    }
    *(short8*)(x_bf + (size_t)node * 256 + c) = ob;
  }
}

// global mean pool: LDS [16][256] block accumulator; global-atomic flush per present graph.
#define PBLK 256
__global__ __launch_bounds__(256) void k_pool(const ushort* __restrict__ x_bf, const int* __restrict__ batch,
                                              float* __restrict__ pooled, float* __restrict__ counts){
  __shared__ float lacc[NGRAPHS][256];
  __shared__ float lcnt[NGRAPHS];
  int tid = threadIdx.x;
  int wave = tid >> 6, lane = tid & 63;
  int c = lane * 4;
#pragma unroll
  for (int g = 0; g < NGRAPHS; ++g) lacc[g][tid] = 0.f;
  if (tid < NGRAPHS) lcnt[tid] = 0.f;
  __syncthreads();

  int n0 = blockIdx.x * PBLK + wave * 64;
  if (n0 < N_NODES){
    int n1 = min(n0 + 64, N_NODES);
    int b0 = batch[n0], b1 = batch[n1 - 1];
    float a0 = 0.f, a1 = 0.f, a2 = 0.f, a3 = 0.f;
    if (b0 == b1){                            // wave-uniform fast path
      int i = n0;
      for (; i + 8 <= n1; i += 8){
        uint2 v[8];
#pragma unroll
        for (int j = 0; j < 8; ++j) v[j] = *(const uint2*)(x_bf + (size_t)(i + j) * 256 + c);
#pragma unroll
        for (int j = 0; j < 8; ++j){
          a0 += bflo(v[j].x); a1 += bfhi(v[j].x);
          a2 += bflo(v[j].y); a3 += bfhi(v[j].y);
        }
      }
      for (; i < n1; ++i){
        uint2 v = *(const uint2*)(x_bf + (size_t)i * 256 + c);
        a0 += bflo(v.x); a1 += bfhi(v.x); a2 += bflo(v.y); a3 += bfhi(v.y);
      }
      atomicAdd(&lacc[b0][c + 0], a0); atomicAdd(&lacc[b0][c + 1], a1);
      atomicAdd(&lacc[b0][c + 2], a2); atomicAdd(&lacc[b0][c + 3], a3);
      if (lane == 0) atomicAdd(&lcnt[b0], (float)(n1 - n0));
    } else {                                  // boundary wave (<=15 per launch)
      int cur = b0, cnt = 0;
      for (int i = n0; i < n1; ++i){
        int g = batch[i];
        if (g != cur){
          atomicAdd(&lacc[cur][c + 0], a0); atomicAdd(&lacc[cur][c + 1], a1);
          atomicAdd(&lacc[cur][c + 2], a2); atomicAdd(&lacc[cur][c + 3], a3);
          if (lane == 0) atomicAdd(&lcnt[cur], (float)cnt);
          a0 = a1 = a2 = a3 = 0.f; cnt = 0; cur = g;
        }
        uint2 v = *(const uint2*)(x_bf + (size_t)i * 256 + c);
        a0 += bflo(v.x); a1 += bfhi(v.x); a2 += bflo(v.y); a3 += bfhi(v.y);
        cnt++;
      }
      atomicAdd(&lacc[cur][c + 0], a0); atomicAdd(&lacc[cur][c + 1], a1);
      atomicAdd(&lacc[cur][c + 2], a2); atomicAdd(&lacc[cur][c + 3], a3);
      if (lane == 0) atomicAdd(&lcnt[cur], (float)cnt);
    }
  }
  __syncthreads();

  int base = blockIdx.x * PBLK;
  if (base < N_NODES){
    int gmin = batch[base];
    int gmax = batch[min(base + PBLK, N_NODES) - 1];
    for (int g = gmin; g <= gmax; ++g){
      float v = lacc[g][tid];
      if (v != 0.f) atomicAdd(&pooled[g * 256 + tid], v);
      if (tid == 0 && lcnt[g] > 0.f) atomicAdd(&counts[g], lcnt[g]);
    }
  }
}

__global__ __launch_bounds__(256) void k_head(const float* __restrict__ pooled, const float* __restrict__ counts,
    const float* __restrict__ params, void* __restrict__ out, const int* __restrict__ flag){
  __shared__ float m[256];
  __shared__ float hh[256];
  __shared__ float red[2][4];
  int g = blockIdx.x, tid = threadIdx.x;
  float cnt = fmaxf(counts[g], 1.f);
  m[tid] = pooled[g * 256 + tid] / cnt;
  __syncthreads();
  const float* W1 = params + OFF_WO1;
  float acc = params[OFF_BO1 + tid];
  for (int k = 0; k < 256; ++k) acc = fmaf(m[k], W1[k * 256 + tid], acc);
  acc = fmaxf(acc, 0.f);
  float s = wave_reduce_sum(acc), ss = wave_reduce_sum(acc * acc);
  int wv = tid >> 6, lane = tid & 63;
  if (lane == 0){ red[0][wv] = s; red[1][wv] = ss; }
  __syncthreads();
  float S  = red[0][0] + red[0][1] + red[0][2] + red[0][3];
  float SS = red[1][0] + red[1][1] + red[1][2] + red[1][3];
  float mean = S * (1.f/256.f);
  float var  = SS * (1.f/256.f) - mean * mean;
  float inv  = rsqrtf(var + EPS);
  float hn = (acc - mean) * inv * params[OFF_GO + tid] + params[OFF_BEO + tid];
  hh[tid] = hn;
  __syncthreads();
  if (tid < ZDIM){
    const float* W2 = params + OFF_WO2;
    float o = params[OFF_BO2 + tid];
    for (int k = 0; k < 256; ++k) o = fmaf(hh[k], W2[k * 128 + tid], o);
    if (*flag) ((float*)out)[g * 128 + tid] = o;
    else       ((__hip_bfloat16*)out)[g * 128 + tid] = __float2bfloat16(o);
  }
}

extern "C" void kernel_launch(void* const* d_in, const int* in_sizes, int n_in,
                              void* d_out, int out_size, void* d_ws, size_t ws_size,
                              hipStream_t stream){
  // ---- workspace layout ----
  size_t o = 0;
  auto alloc = [&](size_t bytes)->size_t{ size_t r = o; o = (o + bytes + 255) & ~(size_t)255; return r; };
  size_t off_flag   = alloc(4);
  size_t off_deg    = alloc((size_t)N_NODES * 4);
  size_t off_dinv   = alloc((size_t)N_NODES * 4);
  size_t off_rs     = alloc((size_t)(N_NODES + 1) * 4);
  size_t off_rs2    = alloc((size_t)(N_NODES + 1) * 4);
  size_t off_fill   = alloc((size_t)N_NODES * 4);
  size_t off_bsum   = alloc((size_t)NSCANBLK * 4);
  size_t off_boff   = alloc((size_t)NSCANBLK * 4);
  size_t off_csr    = alloc((size_t)(N_EDGES + N_NODES) * 8);
  size_t off_params = alloc((size_t)PARAMS_TOTAL * 4);
  size_t off_xbf    = alloc((size_t)N_NODES * HIDDEN * 2);
  size_t off_h8     = alloc((size_t)N_NODES * HIDDEN);       // fp8 h
  size_t off_wt     = alloc((size_t)NLAYERS * HIDDEN * HIDDEN * 2);
  size_t off_pool   = alloc((size_t)NGRAPHS * 256 * 4);
  size_t off_cnt    = alloc((size_t)NGRAPHS * 4);
  if (o > ws_size) return;

  char* ws = (char*)d_ws;
  int*    flag     = (int*)(ws + off_flag);
  int*    deg      = (int*)(ws + off_deg);
  float*  dinv     = (float*)(ws + off_dinv);
  int*    row_start= (int*)(ws + off_rs);
  int*    rs2      = (int*)(ws + off_rs2);
  int*    fill     = (int*)(ws + off_fill);
  int*    bsum     = (int*)(ws + off_bsum);
  int*    boff     = (int*)(ws + off_boff);
  uint2*  csr      = (uint2*)(ws + off_csr);
  float*  params   = (float*)(ws + off_params);
  ushort* x_bf     = (ushort*)(ws + off_xbf);
  unsigned char* h8 = (unsigned char*)(ws + off_h8);
  ushort* Wt       = (ushort*)(ws + off_wt);
  float*  pooled   = (float*)(ws + off_pool);
  float*  counts   = (float*)(ws + off_cnt);

  const int* edge_src = (const int*)d_in[1];               // edge_index[0]
  const int* edge_dst = (const int*)d_in[1] + N_EDGES;     // edge_index[1]
  const int* batch    = (const int*)d_in[2];

  // ---- fused dtype detect + param convert + Wt build + buffer init ----
  PrepArgs pa;
  const int srcIdx[14] = {0,3,4,5,6,8,9,10,11,12,13,14,15,16};
  const int ns[14]     = {150000,768,256,256,256,768,768,768,65536,256,256,256,32768,128};
  const int offs[14]   = {OFF_POS,OFF_WIN,OFF_BIN,OFF_GIN,OFF_BEIN,OFF_CONVB,OFF_GNG,OFF_GNB,
                          OFF_WO1,OFF_BO1,OFF_GO,OFF_BEO,OFF_WO2,OFF_BO2};
  for (int i = 0; i < 14; ++i){ pa.src[i] = d_in[srcIdx[i]]; pa.n[i] = ns[i]; pa.off[i] = offs[i]; }
  pa.win = d_in[3]; pa.convw = d_in[7];
  k_prep<<<512, 256, 0, stream>>>(pa, params, Wt, flag, deg, fill, pooled, counts);

  // ---- graph preprocessing ----
  k_deg<<<(N_EDGES + 255) / 256, 256, 0, stream>>>(edge_dst, deg);
  k_scan1<<<NSCANBLK, 256, 0, stream>>>(deg, row_start, bsum, dinv);
  k_scan2<<<1, 256, 0, stream>>>(bsum, boff, row_start);

  // ---- fused CSR fill (+rs2 finalize) + input projection ----
  int projb = (N_NODES + 3) / 4;
  k_fillproj<<<FILLB + projb, 256, 0, stream>>>(edge_src, edge_dst, row_start, boff, deg, fill,
                                                dinv, csr, rs2, params, x_bf);

  // ---- GCN layers (split: MFMA GEMM -> fp8 h + gather/norm) ----
  dim3 ggrid(2, (N_NODES + GBM - 1) / GBM);
  for (int l = 0; l < NLAYERS; ++l){
    k_gemm_bf<<<ggrid, 256, 0, stream>>>(x_bf, Wt + l * 65536, h8, N_NODES);
    k_agg_norm<<<N_NODES / 4, 256, 0, stream>>>(h8, x_bf, rs2, csr, params, l);
  }

  // ---- pool + head ----
  k_pool<<<(N_NODES + PBLK - 1) / PBLK, 256, 0, stream>>>(x_bf, batch, pooled, counts);
  k_head<<<NGRAPHS, 256, 0, stream>>>(pooled, counts, params, d_out, flag);
}

// Round 13
// 331.924 us; speedup vs baseline: 1.6678x; 1.0167x over previous
//
#include <hip/hip_runtime.h>
#include <hip/hip_bf16.h>

#define N_NODES 50000
#define N_EDGES 300000
#define HIDDEN 256
#define ZDIM 128
#define NLAYERS 3
#define NGRAPHS 16
#define EPS 1e-5f
#define NSCANBLK 196   // ceil(50000/256)
#define FILLB 1368     // ceil((N_EDGES+N_NODES)/256)

// ---- fp32 param region offsets (floats) ----
#define OFF_POS    0
#define OFF_WIN    150000
#define OFF_BIN    150768
#define OFF_GIN    151024
#define OFF_BEIN   151280
#define OFF_CONVB  348144
#define OFF_GNG    348912
#define OFF_GNB    349680
#define OFF_WO1    350448
#define OFF_BO1    415984
#define OFF_GO     416240
#define OFF_BEO    416496
#define OFF_WO2    416752
#define OFF_BO2    449520
#define PARAMS_TOTAL 449648

typedef __attribute__((ext_vector_type(8))) short short8;
typedef __attribute__((ext_vector_type(4))) float floatx4;

__device__ inline float wave_reduce_sum(float v){
#pragma unroll
  for (int off = 32; off; off >>= 1) v += __shfl_xor(v, off);
  return v;
}

__device__ inline ushort f2bf(float f){
  __hip_bfloat16 t = __float2bfloat16(f);
  return *(ushort*)&t;
}
__device__ inline float bflo(unsigned int u){ return __uint_as_float(u << 16); }
__device__ inline float bfhi(unsigned int u){ return __uint_as_float(u & 0xffff0000u); }

__device__ inline void gload_lds16(const void* g, void* l){
  __builtin_amdgcn_global_load_lds((const __attribute__((address_space(1))) void*)g,
                                   (__attribute__((address_space(3))) void*)l, 16, 0, 0);
}

// fp8 e4m3 encode: pack (v,v) and take byte 0 -- immune to pk byte-order convention
__device__ inline unsigned char f2fp8(float v){
  int pk = __builtin_amdgcn_cvt_pk_fp8_f32(v, v, 0, false);
  return (unsigned char)(pk & 0xff);
}

// decode 8 fp8 (one uint2) with explicit byte selects (little-endian: byte k = channel k)
__device__ inline void acc8f(float* a, float w, uint2 v){
  a[0] = fmaf(w, __builtin_amdgcn_cvt_f32_fp8((int)v.x, 0), a[0]);
  a[1] = fmaf(w, __builtin_amdgcn_cvt_f32_fp8((int)v.x, 1), a[1]);
  a[2] = fmaf(w, __builtin_amdgcn_cvt_f32_fp8((int)v.x, 2), a[2]);
  a[3] = fmaf(w, __builtin_amdgcn_cvt_f32_fp8((int)v.x, 3), a[3]);
  a[4] = fmaf(w, __builtin_amdgcn_cvt_f32_fp8((int)v.y, 0), a[4]);
  a[5] = fmaf(w, __builtin_amdgcn_cvt_f32_fp8((int)v.y, 1), a[5]);
  a[6] = fmaf(w, __builtin_amdgcn_cvt_f32_fp8((int)v.y, 2), a[6]);
  a[7] = fmaf(w, __builtin_amdgcn_cvt_f32_fp8((int)v.y, 3), a[7]);
}

struct PrepArgs { const void* src[14]; int n[14]; int off[14]; const void* win; const void* convw; };

// fused: dtype detect + param convert + coalesced Wt build (blocks 0..47) + buffer init
__global__ __launch_bounds__(256) void k_prep(PrepArgs a, float* __restrict__ params,
                                              ushort* __restrict__ Wt, int* __restrict__ flag,
                                              int* __restrict__ deg, int* __restrict__ fill,
                                              float* __restrict__ pooled, float* __restrict__ counts){
  __shared__ int sf;
  __shared__ ushort tile[64][72];     // 64x64 transpose tile, padded
  int tid = threadIdx.x;
  if (tid == 0) sf = 0;
  __syncthreads();
  const unsigned short* w = (const unsigned short*)a.win;
  for (int i = tid; i < 768; i += 256){
    int e = (w[i] >> 7) & 0xff;            // bf16 exponent field
    if (e >= 148) atomicOr(&sf, 1);        // |v|>=2^20: impossible for real bf16 weights
  }
  __syncthreads();
  const bool isf32 = (sf != 0);
  if (blockIdx.x == 0 && tid == 0) *flag = sf;

  // Wt[l][n][k] = conv_W[l][k][n] as bf16 -- one 64x64 tile per block, LDS transpose
  if (blockIdx.x < NLAYERS * 16){
    int t = blockIdx.x;
    int l = t >> 4, tt = t & 15;
    int kr0 = (tt >> 2) * 64, nc0 = (tt & 3) * 64;
    size_t base = (size_t)l * 65536;
    int r = tid >> 2;                 // 0..63
    int seg = (tid & 3) * 16;         // 0,16,32,48
    if (isf32){
      const float* srcp = (const float*)a.convw + base + (size_t)(kr0 + r) * 256 + nc0 + seg;
#pragma unroll
      for (int j = 0; j < 16; ++j) tile[r][seg + j] = f2bf(srcp[j]);
    } else {
      const unsigned short* srcp = (const unsigned short*)a.convw + base + (size_t)(kr0 + r) * 256 + nc0 + seg;
#pragma unroll
      for (int j = 0; j < 16; ++j) tile[r][seg + j] = srcp[j];
    }
    __syncthreads();
    ushort* dst = Wt + base + (size_t)(nc0 + r) * 256 + kr0 + seg;   // r = n here
#pragma unroll
    for (int j = 0; j < 16; ++j) dst[j] = tile[seg + j][r];
  }

  int stride = gridDim.x * blockDim.x;
  int t0 = blockIdx.x * blockDim.x + tid;
  // init side-buffers (self-loop contributes deg=1)
  for (int i = t0; i < N_NODES; i += stride){ deg[i] = 1; fill[i] = 0; }
  for (int i = t0; i < NGRAPHS * 256; i += stride) pooled[i] = 0.f;
  for (int i = t0; i < NGRAPHS; i += stride) counts[i] = 0.f;

  for (int s = 0; s < 14; ++s){
    const void* src = a.src[s];
    int n = a.n[s];
    float* dst = params + a.off[s];
    if (isf32){
      const float* f = (const float*)src;
      for (int i = t0; i < n; i += stride) dst[i] = f[i];
    } else {
      const unsigned short* u = (const unsigned short*)src;
      for (int i = t0; i < n; i += stride) dst[i] = bflo(u[i]);
    }
  }
}

__global__ void k_deg(const int* __restrict__ dst, int* __restrict__ deg){
  int e = blockIdx.x * blockDim.x + threadIdx.x;
  if (e < N_EDGES) atomicAdd(&deg[dst[e]], 1);
}

// ---- hierarchical scan of deg (+ fused dinv) ----
__global__ __launch_bounds__(256) void k_scan1(const int* __restrict__ deg, int* __restrict__ row_start,
                                               int* __restrict__ bsum, float* __restrict__ dinv){
  __shared__ int sd[256];
  int tid = threadIdx.x;
  int i = blockIdx.x * 256 + tid;
  int v = (i < N_NODES) ? deg[i] : 0;
  if (i < N_NODES) dinv[i] = rsqrtf((float)v);
  sd[tid] = v;
  __syncthreads();
#pragma unroll
  for (int off = 1; off < 256; off <<= 1){
    int t = (tid >= off) ? sd[tid - off] : 0;
    __syncthreads();
    sd[tid] += t;
    __syncthreads();
  }
  if (i < N_NODES) row_start[i] = sd[tid];    // inclusive within block
  if (tid == 255) bsum[blockIdx.x] = sd[255];
}

__global__ __launch_bounds__(256) void k_scan2(const int* __restrict__ bsum, int* __restrict__ boff,
                                               int* __restrict__ row_start){
  __shared__ int sd[256];
  int tid = threadIdx.x;
  int v = (tid < NSCANBLK) ? bsum[tid] : 0;
  sd[tid] = v;
  __syncthreads();
#pragma unroll
  for (int off = 1; off < 256; off <<= 1){
    int t = (tid >= off) ? sd[tid - off] : 0;
    __syncthreads();
    sd[tid] += t;
    __syncthreads();
  }
  if (tid < NSCANBLK) boff[tid] = sd[tid] - v;   // exclusive block offset
  if (tid == NSCANBLK - 1) row_start[N_NODES] = sd[tid];
}

// fused: CSR fill (final row offsets on the fly; rs2 finalized by self-loop threads)
// + input projection (blocks >= FILLB).
__global__ __launch_bounds__(256) void k_fillproj(const int* __restrict__ src, const int* __restrict__ dst,
    const int* __restrict__ row_start, const int* __restrict__ boff, const int* __restrict__ deg,
    int* __restrict__ fill, const float* __restrict__ dinv, uint2* __restrict__ csr,
    int* __restrict__ rs2, const float* __restrict__ params, ushort* __restrict__ x_bf){
  int b = blockIdx.x, tid = threadIdx.x;
  if (b < FILLB){
    int t = b * 256 + tid;
    if (t == 0) rs2[N_NODES] = row_start[N_NODES];
    if (t < N_EDGES + N_NODES){
      int s, d;
      if (t < N_EDGES){ s = src[t]; d = dst[t]; }
      else            { s = t - N_EDGES; d = s; }      // self loops
      int rsf = row_start[d] + boff[d >> 8] - deg[d];  // final exclusive start of node d
      int pos = rsf + atomicAdd(&fill[d], 1);
      uint2 e; e.x = (unsigned)s; e.y = __float_as_uint(dinv[s] * dinv[d]);
      csr[pos] = e;
      if (t >= N_EDGES) rs2[s] = rsf;                  // materialize finalized offsets
    }
    return;
  }
  // ---- input projection: one wave per node ----
  int lane = tid & 63;
  int node = ((b - FILLB) << 2) + (tid >> 6);
  if (node >= N_NODES) return;
  const float* pos = params + OFF_POS + node * 3;
  float px = pos[0], py = pos[1], pz = pos[2];
  int c = lane * 4;
  const float* w0 = params + OFF_WIN;
  float v[4];
#pragma unroll
  for (int j = 0; j < 4; ++j){
    float t = params[OFF_BIN + c + j];
    t = fmaf(px, w0[c + j], t);
    t = fmaf(py, w0[256 + c + j], t);
    t = fmaf(pz, w0[512 + c + j], t);
    v[j] = fmaxf(t, 0.f);
  }
  float s  = v[0] + v[1] + v[2] + v[3];
  float ss = v[0]*v[0] + v[1]*v[1] + v[2]*v[2] + v[3]*v[3];
  s = wave_reduce_sum(s); ss = wave_reduce_sum(ss);
  float mean = s * (1.f/256.f);
  float var  = ss * (1.f/256.f) - mean * mean;
  float inv  = rsqrtf(var + EPS);
  float4 o;
  o.x = (v[0]-mean)*inv*params[OFF_GIN+c+0] + params[OFF_BEIN+c+0];
  o.y = (v[1]-mean)*inv*params[OFF_GIN+c+1] + params[OFF_BEIN+c+1];
  o.z = (v[2]-mean)*inv*params[OFF_GIN+c+2] + params[OFF_BEIN+c+2];
  o.w = (v[3]-mean)*inv*params[OFF_GIN+c+3] + params[OFF_BEIN+c+3];
  ushort4 ob = { f2bf(o.x), f2bf(o.y), f2bf(o.z), f2bf(o.w) };
  *(ushort4*)(x_bf + node * 256 + c) = ob;
}

// bf16 MFMA GEMM: C(Mx256, fp8-e4m3 out) = A(Mx256 bf16) @ Wt^T.  Wt is [n][k].
// 128x128 tile, BK=64, async global_load_lds (16B) staging with XOR granule swizzle.
#define GBM 128
__global__ __launch_bounds__(256) void k_gemm_bf(const ushort* __restrict__ A, const ushort* __restrict__ Bt,
                                                 unsigned char* __restrict__ Cb, int M){
  __shared__ __align__(16) ushort Sh[2 * GBM * 64];   // As | Bs
  ushort* As = Sh;
  ushort* Bs = Sh + GBM * 64;
  int tid = threadIdx.x;
  int wave = tid >> 6, lane = tid & 63;
  int wr = wave >> 1, wc = wave & 1;
  int row0 = blockIdx.y * GBM;
  int col0 = blockIdx.x * GBM;
  int q = lane >> 4, l15 = lane & 15;
  int srow = lane >> 3;      // row within 8-row staging group
  int sg   = lane & 7;       // destination granule
  floatx4 acc[4][4] = {};
  for (int k0 = 0; k0 < 256; k0 += 64){
    __syncthreads();
#pragma unroll
    for (int t = 0; t < 4; ++t){
      int rg = wave * 4 + t;               // 8-row group 0..15
      int r  = rg * 8 + srow;              // tile row 0..127
      int gs = sg ^ (r & 7);               // swizzled SOURCE granule
      const ushort* ga = A  + (size_t)(row0 + r) * 256 + k0 + gs * 8;  // tail rows: valid ws memory, never stored
      const ushort* gb = Bt + (size_t)(col0 + r) * 256 + k0 + gs * 8;
      gload_lds16(ga, As + rg * 512);
      gload_lds16(gb, Bs + rg * 512);
    }
    __syncthreads();
#pragma unroll
    for (int kk = 0; kk < 64; kk += 32){
      short8 af[4], bfr[4];
#pragma unroll
      for (int i = 0; i < 4; ++i){
        int R = wr * 64 + i * 16 + l15;
        int bg = (kk >> 3) + q;                       // logical granule 0..7
        af[i] = *(const short8*)(As + R * 64 + ((bg ^ (R & 7)) << 3));
      }
#pragma unroll
      for (int j = 0; j < 4; ++j){
        int C = wc * 64 + j * 16 + l15;
        int bg = (kk >> 3) + q;
        bfr[j] = *(const short8*)(Bs + C * 64 + ((bg ^ (C & 7)) << 3));
      }
#pragma unroll
      for (int i = 0; i < 4; ++i)
#pragma unroll
        for (int j = 0; j < 4; ++j)
          acc[i][j] = __builtin_amdgcn_mfma_f32_16x16x32_bf16(af[i], bfr[j], acc[i][j], 0, 0, 0);
    }
  }
#pragma unroll
  for (int i = 0; i < 4; ++i){
#pragma unroll
    for (int r = 0; r < 4; ++r){
      int row = row0 + wr * 64 + i * 16 + q * 4 + r;
      if (row < M){
#pragma unroll
        for (int j = 0; j < 4; ++j){
          int col = col0 + wc * 64 + j * 16 + l15;
          Cb[(size_t)row * 256 + col] = f2fp8(acc[i][j][r]);
        }
      }
    }
  }
}

// aggregate over packed CSR (fp8 h) + bias + GroupNorm + ReLU + residual (bf16 x, in-place).
// v4: cooperative CSR-row load (rows are contiguous; lane i holds entry p0+i), neighbor
// (src,w) distributed via shfl -- removes the serial csr-load -> gather dependency chain.
// Half-waves keep the p / p+1 parity split; accumulation order identical to v3.
__global__ __launch_bounds__(256) void k_agg_norm(const unsigned char* __restrict__ hb,
    ushort* __restrict__ x_bf, const int* __restrict__ rs2, const uint2* __restrict__ csr,
    const float* __restrict__ params, int layer){
  int lane = threadIdx.x & 63;
  int node = (blockIdx.x << 2) + (threadIdx.x >> 6);
  if (node >= N_NODES) return;
  int half = lane >> 5;
  int l32 = lane & 31;
  int c = l32 * 8;
  int p0 = rs2[node], p1 = rs2[node + 1];
  int dg = p1 - p0;
  // cooperative row load: one coalesced access covers the whole (contiguous) CSR row
  uint2 el = {0u, 0u};
  if (lane < dg) el = csr[p0 + lane];
  int ex = (int)el.x, ew = (int)el.y;
  float a[8] = {};
  int nt = (dg > 64) ? 64 : dg;
  int cnt = (nt - half + 1) >> 1;        // neighbors of this parity among first 64
  int t = 0;
  for (; t + 4 <= cnt; t += 4){
    int j0 = (t + 0) * 2 + half, j1 = (t + 1) * 2 + half;
    int j2 = (t + 2) * 2 + half, j3 = (t + 3) * 2 + half;
    int s0 = __shfl(ex, j0), s1 = __shfl(ex, j1), s2 = __shfl(ex, j2), s3 = __shfl(ex, j3);
    float w0 = __uint_as_float((unsigned)__shfl(ew, j0));
    float w1 = __uint_as_float((unsigned)__shfl(ew, j1));
    float w2 = __uint_as_float((unsigned)__shfl(ew, j2));
    float w3 = __uint_as_float((unsigned)__shfl(ew, j3));
    uint2 v0 = *(const uint2*)(hb + (size_t)(unsigned)s0 * 256 + c);
    uint2 v1 = *(const uint2*)(hb + (size_t)(unsigned)s1 * 256 + c);
    uint2 v2 = *(const uint2*)(hb + (size_t)(unsigned)s2 * 256 + c);
    uint2 v3 = *(const uint2*)(hb + (size_t)(unsigned)s3 * 256 + c);
    acc8f(a, w0, v0); acc8f(a, w1, v1); acc8f(a, w2, v2); acc8f(a, w3, v3);
  }
  for (; t < cnt; ++t){
    int j = t * 2 + half;
    int s0 = __shfl(ex, j);
    float w0 = __uint_as_float((unsigned)__shfl(ew, j));
    uint2 v0 = *(const uint2*)(hb + (size_t)(unsigned)s0 * 256 + c);
    acc8f(a, w0, v0);
  }
  // rare deg>64 tail: direct loads, same parity split and ascending order
  for (int p = p0 + 64 + half; p < p1; p += 2){
    uint2 e = csr[p];
    uint2 v = *(const uint2*)(hb + (size_t)e.x * 256 + c);
    acc8f(a, __uint_as_float(e.y), v);
  }
#pragma unroll
  for (int j = 0; j < 8; ++j) a[j] += __shfl_xor(a[j], 32);

  const float* cb = params + OFF_CONVB + layer * 256;
  float v8[8];
  float s = 0.f, ss = 0.f;
#pragma unroll
  for (int j = 0; j < 8; ++j){
    float t2 = a[j] + cb[c + j];
    v8[j] = t2; s += t2; ss += t2 * t2;
  }
  s  = wave_reduce_sum(s)  * 0.5f;    // each channel counted exactly twice
  ss = wave_reduce_sum(ss) * 0.5f;
  float mean = s * (1.f/256.f);
  float var  = ss * (1.f/256.f) - mean * mean;
  float inv  = rsqrtf(var + EPS);
  if (half == 0){
    const float* g = params + OFF_GNG + layer * 256;
    const float* b = params + OFF_GNB + layer * 256;
    uint4 xo = *(const uint4*)(x_bf + (size_t)node * 256 + c);
    float xr[8] = { bflo(xo.x), bfhi(xo.x), bflo(xo.y), bfhi(xo.y),
                    bflo(xo.z), bfhi(xo.z), bflo(xo.w), bfhi(xo.w) };
    short8 ob;
#pragma unroll
    for (int j = 0; j < 8; ++j){
      float o = fmaxf((v8[j] - mean) * inv * g[c + j] + b[c + j], 0.f) + xr[j];
      ob[j] = (short)f2bf(o);
    }
    *(short8*)(x_bf + (size_t)node * 256 + c) = ob;
  }
}

// global mean pool: LDS [16][256] block accumulator; global-atomic flush per present graph.
#define PBLK 256
__global__ __launch_bounds__(256) void k_pool(const ushort* __restrict__ x_bf, const int* __restrict__ batch,
                                              float* __restrict__ pooled, float* __restrict__ counts){
  __shared__ float lacc[NGRAPHS][256];
  __shared__ float lcnt[NGRAPHS];
  int tid = threadIdx.x;
  int wave = tid >> 6, lane = tid & 63;
  int c = lane * 4;
#pragma unroll
  for (int g = 0; g < NGRAPHS; ++g) lacc[g][tid] = 0.f;
  if (tid < NGRAPHS) lcnt[tid] = 0.f;
  __syncthreads();

  int n0 = blockIdx.x * PBLK + wave * 64;
  if (n0 < N_NODES){
    int n1 = min(n0 + 64, N_NODES);
    int b0 = batch[n0], b1 = batch[n1 - 1];
    float a0 = 0.f, a1 = 0.f, a2 = 0.f, a3 = 0.f;
    if (b0 == b1){                            // wave-uniform fast path
      int i = n0;
      for (; i + 8 <= n1; i += 8){
        uint2 v[8];
#pragma unroll
        for (int j = 0; j < 8; ++j) v[j] = *(const uint2*)(x_bf + (size_t)(i + j) * 256 + c);
#pragma unroll
        for (int j = 0; j < 8; ++j){
          a0 += bflo(v[j].x); a1 += bfhi(v[j].x);
          a2 += bflo(v[j].y); a3 += bfhi(v[j].y);
        }
      }
      for (; i < n1; ++i){
        uint2 v = *(const uint2*)(x_bf + (size_t)i * 256 + c);
        a0 += bflo(v.x); a1 += bfhi(v.x); a2 += bflo(v.y); a3 += bfhi(v.y);
      }
      atomicAdd(&lacc[b0][c + 0], a0); atomicAdd(&lacc[b0][c + 1], a1);
      atomicAdd(&lacc[b0][c + 2], a2); atomicAdd(&lacc[b0][c + 3], a3);
      if (lane == 0) atomicAdd(&lcnt[b0], (float)(n1 - n0));
    } else {                                  // boundary wave (<=15 per launch)
      int cur = b0, cnt = 0;
      for (int i = n0; i < n1; ++i){
        int g = batch[i];
        if (g != cur){
          atomicAdd(&lacc[cur][c + 0], a0); atomicAdd(&lacc[cur][c + 1], a1);
          atomicAdd(&lacc[cur][c + 2], a2); atomicAdd(&lacc[cur][c + 3], a3);
          if (lane == 0) atomicAdd(&lcnt[cur], (float)cnt);
          a0 = a1 = a2 = a3 = 0.f; cnt = 0; cur = g;
        }
        uint2 v = *(const uint2*)(x_bf + (size_t)i * 256 + c);
        a0 += bflo(v.x); a1 += bfhi(v.x); a2 += bflo(v.y); a3 += bfhi(v.y);
        cnt++;
      }
      atomicAdd(&lacc[cur][c + 0], a0); atomicAdd(&lacc[cur][c + 1], a1);
      atomicAdd(&lacc[cur][c + 2], a2); atomicAdd(&lacc[cur][c + 3], a3);
      if (lane == 0) atomicAdd(&lcnt[cur], (float)cnt);
    }
  }
  __syncthreads();

  int base = blockIdx.x * PBLK;
  if (base < N_NODES){
    int gmin = batch[base];
    int gmax = batch[min(base + PBLK, N_NODES) - 1];
    for (int g = gmin; g <= gmax; ++g){
      float v = lacc[g][tid];
      if (v != 0.f) atomicAdd(&pooled[g * 256 + tid], v);
      if (tid == 0 && lcnt[g] > 0.f) atomicAdd(&counts[g], lcnt[g]);
    }
  }
}

__global__ __launch_bounds__(256) void k_head(const float* __restrict__ pooled, const float* __restrict__ counts,
    const float* __restrict__ params, void* __restrict__ out, const int* __restrict__ flag){
  __shared__ float m[256];
  __shared__ float hh[256];
  __shared__ float red[2][4];
  int g = blockIdx.x, tid = threadIdx.x;
  float cnt = fmaxf(counts[g], 1.f);
  m[tid] = pooled[g * 256 + tid] / cnt;
  __syncthreads();
  const float* W1 = params + OFF_WO1;
  float acc = params[OFF_BO1 + tid];
  for (int k = 0; k < 256; ++k) acc = fmaf(m[k], W1[k * 256 + tid], acc);
  acc = fmaxf(acc, 0.f);
  float s = wave_reduce_sum(acc), ss = wave_reduce_sum(acc * acc);
  int wv = tid >> 6, lane = tid & 63;
  if (lane == 0){ red[0][wv] = s; red[1][wv] = ss; }
  __syncthreads();
  float S  = red[0][0] + red[0][1] + red[0][2] + red[0][3];
  float SS = red[1][0] + red[1][1] + red[1][2] + red[1][3];
  float mean = S * (1.f/256.f);
  float var  = SS * (1.f/256.f) - mean * mean;
  float inv  = rsqrtf(var + EPS);
  float hn = (acc - mean) * inv * params[OFF_GO + tid] + params[OFF_BEO + tid];
  hh[tid] = hn;
  __syncthreads();
  if (tid < ZDIM){
    const float* W2 = params + OFF_WO2;
    float o = params[OFF_BO2 + tid];
    for (int k = 0; k < 256; ++k) o = fmaf(hh[k], W2[k * 128 + tid], o);
    if (*flag) ((float*)out)[g * 128 + tid] = o;
    else       ((__hip_bfloat16*)out)[g * 128 + tid] = __float2bfloat16(o);
  }
}

extern "C" void kernel_launch(void* const* d_in, const int* in_sizes, int n_in,
                              void* d_out, int out_size, void* d_ws, size_t ws_size,
                              hipStream_t stream){
  // ---- workspace layout ----
  size_t o = 0;
  auto alloc = [&](size_t bytes)->size_t{ size_t r = o; o = (o + bytes + 255) & ~(size_t)255; return r; };
  size_t off_flag   = alloc(4);
  size_t off_deg    = alloc((size_t)N_NODES * 4);
  size_t off_dinv   = alloc((size_t)N_NODES * 4);
  size_t off_rs     = alloc((size_t)(N_NODES + 1) * 4);
  size_t off_rs2    = alloc((size_t)(N_NODES + 1) * 4);
  size_t off_fill   = alloc((size_t)N_NODES * 4);
  size_t off_bsum   = alloc((size_t)NSCANBLK * 4);
  size_t off_boff   = alloc((size_t)NSCANBLK * 4);
  size_t off_csr    = alloc((size_t)(N_EDGES + N_NODES) * 8);
  size_t off_params = alloc((size_t)PARAMS_TOTAL * 4);
  size_t off_xbf    = alloc((size_t)N_NODES * HIDDEN * 2);
  size_t off_h8     = alloc((size_t)N_NODES * HIDDEN);       // fp8 h
  size_t off_wt     = alloc((size_t)NLAYERS * HIDDEN * HIDDEN * 2);
  size_t off_pool   = alloc((size_t)NGRAPHS * 256 * 4);
  size_t off_cnt    = alloc((size_t)NGRAPHS * 4);
  if (o > ws_size) return;

  char* ws = (char*)d_ws;
  int*    flag     = (int*)(ws + off_flag);
  int*    deg      = (int*)(ws + off_deg);
  float*  dinv     = (float*)(ws + off_dinv);
  int*    row_start= (int*)(ws + off_rs);
  int*    rs2      = (int*)(ws + off_rs2);
  int*    fill     = (int*)(ws + off_fill);
  int*    bsum     = (int*)(ws + off_bsum);
  int*    boff     = (int*)(ws + off_boff);
  uint2*  csr      = (uint2*)(ws + off_csr);
  float*  params   = (float*)(ws + off_params);
  ushort* x_bf     = (ushort*)(ws + off_xbf);
  unsigned char* h8 = (unsigned char*)(ws + off_h8);
  ushort* Wt       = (ushort*)(ws + off_wt);
  float*  pooled   = (float*)(ws + off_pool);
  float*  counts   = (float*)(ws + off_cnt);

  const int* edge_src = (const int*)d_in[1];               // edge_index[0]
  const int* edge_dst = (const int*)d_in[1] + N_EDGES;     // edge_index[1]
  const int* batch    = (const int*)d_in[2];

  // ---- fused dtype detect + param convert + Wt build + buffer init ----
  PrepArgs pa;
  const int srcIdx[14] = {0,3,4,5,6,8,9,10,11,12,13,14,15,16};
  const int ns[14]     = {150000,768,256,256,256,768,768,768,65536,256,256,256,32768,128};
  const int offs[14]   = {OFF_POS,OFF_WIN,OFF_BIN,OFF_GIN,OFF_BEIN,OFF_CONVB,OFF_GNG,OFF_GNB,
                          OFF_WO1,OFF_BO1,OFF_GO,OFF_BEO,OFF_WO2,OFF_BO2};
  for (int i = 0; i < 14; ++i){ pa.src[i] = d_in[srcIdx[i]]; pa.n[i] = ns[i]; pa.off[i] = offs[i]; }
  pa.win = d_in[3]; pa.convw = d_in[7];
  k_prep<<<512, 256, 0, stream>>>(pa, params, Wt, flag, deg, fill, pooled, counts);

  // ---- graph preprocessing ----
  k_deg<<<(N_EDGES + 255) / 256, 256, 0, stream>>>(edge_dst, deg);
  k_scan1<<<NSCANBLK, 256, 0, stream>>>(deg, row_start, bsum, dinv);
  k_scan2<<<1, 256, 0, stream>>>(bsum, boff, row_start);

  // ---- fused CSR fill (+rs2 finalize) + input projection ----
  int projb = (N_NODES + 3) / 4;
  k_fillproj<<<FILLB + projb, 256, 0, stream>>>(edge_src, edge_dst, row_start, boff, deg, fill,
                                                dinv, csr, rs2, params, x_bf);

  // ---- GCN layers (split: MFMA GEMM -> fp8 h + gather/norm) ----
  dim3 ggrid(2, (N_NODES + GBM - 1) / GBM);
  for (int l = 0; l < NLAYERS; ++l){
    k_gemm_bf<<<ggrid, 256, 0, stream>>>(x_bf, Wt + l * 65536, h8, N_NODES);
    k_agg_norm<<<N_NODES / 4, 256, 0, stream>>>(h8, x_bf, rs2, csr, params, l);
  }

  // ---- pool + head ----
  k_pool<<<(N_NODES + PBLK - 1) / PBLK, 256, 0, stream>>>(x_bf, batch, pooled, counts);
  k_head<<<NGRAPHS, 256, 0, stream>>>(pooled, counts, params, d_out, flag);
}